// Round 8
// baseline (776.384 us; speedup 1.0000x reference)
//
#include <hip/hip_runtime.h>
#include <hip/hip_bf16.h>

static const int kN  = 25600;   // nodes
static const int kE  = 409600;  // edges
static const int kG  = 128;     // graphs
static const int kNPG = 200;    // nodes per graph
static const int kIN = 200;     // raw feat dim
static const int kIN2 = 400;    // after nan-mask concat
static const int kK0 = 448;     // layer-0 K padded to 64-multiple for global_load_lds
static const int kMD = 64;      // padded CSR max degree (mean 16, sigma 4 -> 12 sigma)
#define BN_EPS_ 1e-5f

typedef __attribute__((ext_vector_type(8))) short short8;
typedef __attribute__((ext_vector_type(4))) ushort us4;
typedef __attribute__((ext_vector_type(4))) float f32x4;

__device__ __forceinline__ float bu(ushort u) {
  union { float f; unsigned u32; } x; x.u32 = ((unsigned)u) << 16; return x.f;
}
__device__ __forceinline__ ushort f2u(float v) {
  __hip_bfloat16 t = __float2bfloat16(v);  // RN
  return *(ushort*)&t;
}
__device__ __forceinline__ float wredSum(float v) {
#pragma unroll
  for (int off = 1; off < 64; off <<= 1) v += __shfl_xor(v, off, 64);
  return v;
}
__device__ __forceinline__ float lrelu(float a) { return (a > 0.f) ? a : 0.2f * a; }

// async global->LDS, 16B per lane; dest = wave-uniform base + lane*16
#define GLOAD16(g, l) __builtin_amdgcn_global_load_lds( \
    (const __attribute__((address_space(1))) unsigned int*)(g), \
    (__attribute__((address_space(3))) unsigned int*)(l), 16, 0, 0)

// ---- fused prep: prep_x | Wt + wedot | edge-degree + direct scatter | pads --
// pb regions: [0,720) Wt, [720,723) wedot, [723,2323) edges, [2323,2929) pads
__global__ void k_pre(const float* __restrict__ x, ushort* __restrict__ x2,
                      const float* __restrict__ W0, ushort* __restrict__ Wt0,
                      const float* __restrict__ W1, ushort* __restrict__ Wt1,
                      const float* __restrict__ W2, ushort* __restrict__ Wt2,
                      const float* __restrict__ We0, const float* __restrict__ ae0,
                      const float* __restrict__ We1, const float* __restrict__ ae1,
                      const float* __restrict__ We2, const float* __restrict__ ae2,
                      float* __restrict__ wed,
                      const int* __restrict__ ei, const float* __restrict__ ea,
                      int2* __restrict__ epk, int* __restrict__ deg) {
  int b = blockIdx.x, tid = threadIdx.x;
  if (b < 5000) {
    int i4 = (b * 256 + tid) * 4;          // kIN=200 divisible by 4
    int n = i4 / kIN, j = i4 - n * kIN;
    float4 v = *(const float4*)&x[i4];
    ushort o0[4], o1[4];
    float vv[4] = {v.x, v.y, v.z, v.w};
#pragma unroll
    for (int q = 0; q < 4; q++) {
      bool bad = (vv[q] != vv[q]);
      o0[q] = f2u(bad ? 0.f : vv[q]);
      o1[q] = f2u(bad ? 1.f : 0.f);
    }
    *(us4*)&x2[(size_t)n * kK0 + j] = *(us4*)o0;
    *(us4*)&x2[(size_t)n * kK0 + kIN + j] = *(us4*)o1;
    return;
  }
  int pb = b - 5000;
  if (pb >= 2323) {
    // zero the K-pad [400,448) of x2 rows and Wt0 rows (16B stores)
    int idx = (pb - 2323) * 256 + tid;
    short8 z = {0, 0, 0, 0, 0, 0, 0, 0};
    if (idx < 153600) {
      int row = idx / 6, c = idx - row * 6;
      *(short8*)&x2[(size_t)row * kK0 + kIN2 + c * 8] = z;
    } else {
      int j = idx - 153600;
      if (j < 1536) {
        int row = j / 6, c = j - row * 6;
        *(short8*)&Wt0[(size_t)row * kK0 + kIN2 + c * 8] = z;
      }
    }
    return;
  }
  if (pb >= 723) {
    // per-edge: degree count + direct scatter into padded CSR (deg pre-zeroed)
    int e = (pb - 723) * 256 + tid;
    int d = ei[kE + e];
    int s = ei[e];
    float v = ea[e];
    if (v != v) v = 0.f;
    int slot = atomicAdd(&deg[d], 1);
    if (slot < kMD) {
      int2 rec; rec.x = s; rec.y = __float_as_int(v);
      epk[(size_t)d * kMD + slot] = rec;
    }
    return;
  }
  if (pb >= 720) {
    int l = pb - 720;
    const float* We = (l == 0) ? We0 : (l == 1) ? We1 : We2;
    const float* ae = (l == 0) ? ae0 : (l == 1) ? ae1 : ae2;
    int n = (l == 2) ? 64 : 256;
    float v = (tid < n) ? We[tid] * ae[tid] : 0.f;
    v = wredSum(v);
    if ((tid & 63) == 0 && tid < n) wed[l * 4 + (tid >> 6)] = v;
    return;
  }
  int i = pb * 256 + tid;
  if (i < 102400) {
    int n = i / kIN2, k = i - n * kIN2;            // N=256, K=400 (stride 448)
    Wt0[(size_t)n * kK0 + k] = f2u(W0[(size_t)k * 256 + n]);
  } else if (i < 102400 + 65536) {
    int j = i - 102400;
    int n = j >> 8, k = j & 255;                   // N=256, K=256
    Wt1[(size_t)n * 256 + k] = f2u(W1[(size_t)k * 256 + n]);
  } else {
    int j = i - 102400 - 65536;
    int n = j >> 8, k = j & 255;                   // N=64, K=256
    Wt2[(size_t)n * 256 + k] = f2u(W2[(size_t)k * 64 + n]);
  }
}

// ---------------- MFMA GEMM + fused attention dots --------------------------
// LDS staging via global_load_lds, XOR swizzle on the SOURCE address;
// linear LDS [rows][64], 16B chunk c of row r holds global chunk c^(r&7).
// K must be a multiple of 64.
template <int BN, int MT>
__global__ __launch_bounds__(256) void k_gemm_f(const ushort* __restrict__ A,
                                                const ushort* __restrict__ Bt,
                                                ushort* __restrict__ C,
                                                const float* __restrict__ as_g,
                                                const float* __restrict__ ad_g,
                                                float* __restrict__ a_sg,
                                                float* __restrict__ a_dg, int K) {
  constexpr int MI = (BN == 256) ? (MT / 16) : 1;
  constexpr int H = (BN == 256) ? 4 : 1;
  __shared__ ushort As[MT * 64];
  __shared__ ushort Bs[BN * 64];
  int tid = threadIdx.x;
  int lane = tid & 63, w = tid >> 6;
  int l15 = lane & 15, l4 = lane >> 4;
  int row0 = blockIdx.y * MT;
  int wr = (BN == 256) ? 0 : (w * 16);
  int wc = (BN == 256) ? (w * 64) : 0;
  f32x4 acc[MI][4] = {};
  int srow = lane >> 3;   // row within 8-row staging group
  int schunk = lane & 7;  // 16B chunk within 128B row

  for (int kt = 0; kt < K; kt += 64) {
    __syncthreads();
#pragma unroll
    for (int i = 0; i < MT / 32; i++) {
      int ra = w * (MT / 4) + i * 8;
      int r = ra + srow;
      GLOAD16(&A[(size_t)(row0 + r) * K + kt + ((schunk ^ (r & 7)) * 8)],
              &As[ra * 64]);
    }
#pragma unroll
    for (int i = 0; i < BN / 32; i++) {
      int rb = w * (BN / 4) + i * 8;
      int r = rb + srow;
      GLOAD16(&Bt[(size_t)r * K + kt + ((schunk ^ (r & 7)) * 8)],
              &Bs[rb * 64]);
    }
    __syncthreads();  // drains vmcnt before barrier
#pragma unroll
    for (int kk = 0; kk < 2; kk++) {
      short8 af[MI], bf[4];
#pragma unroll
      for (int mi = 0; mi < MI; mi++) {
        int r = wr + mi * 16 + l15;
        af[mi] = *(const short8*)&As[r * 64 + ((kk * 32 + l4 * 8) ^ ((r & 7) * 8))];
      }
#pragma unroll
      for (int ni = 0; ni < 4; ni++) {
        int r = wc + ni * 16 + l15;
        bf[ni] = *(const short8*)&Bs[r * 64 + ((kk * 32 + l4 * 8) ^ ((r & 7) * 8))];
      }
#pragma unroll
      for (int mi = 0; mi < MI; mi++)
#pragma unroll
        for (int ni = 0; ni < 4; ni++)
          acc[mi][ni] = __builtin_amdgcn_mfma_f32_16x16x32_bf16(af[mi], bf[ni],
                                                                acc[mi][ni], 0, 0, 0);
    }
  }
#pragma unroll
  for (int mi = 0; mi < MI; mi++) {
    int rbase = row0 + wr + mi * 16 + l4 * 4;
#pragma unroll
    for (int ni = 0; ni < 4; ni++) {
      int col = wc + ni * 16 + l15;
#pragma unroll
      for (int r = 0; r < 4; r++)
        C[(size_t)(rbase + r) * BN + col] = f2u(acc[mi][ni][r]);
    }
  }
  float asv[4], adv[4];
#pragma unroll
  for (int ni = 0; ni < 4; ni++) {
    asv[ni] = as_g[wc + ni * 16 + l15];
    adv[ni] = ad_g[wc + ni * 16 + l15];
  }
  int hh = (BN == 256) ? w : 0;
#pragma unroll
  for (int mi = 0; mi < MI; mi++) {
#pragma unroll
    for (int r = 0; r < 4; r++) {
      float ps = 0.f, pd = 0.f;
#pragma unroll
      for (int ni = 0; ni < 4; ni++) {
        ps += acc[mi][ni][r] * asv[ni];
        pd += acc[mi][ni][r] * adv[ni];
      }
#pragma unroll
      for (int off = 1; off < 16; off <<= 1) {
        ps += __shfl_xor(ps, off, 64);
        pd += __shfl_xor(pd, off, 64);
      }
      if (l15 == 0) {
        int row = row0 + wr + mi * 16 + l4 * 4 + r;
        a_sg[row * H + hh] = ps;
        a_dg[row * H + hh] = pd;
      }
    }
  }
}

// ---- fused logit+softmax+aggregate, H=4, two-phase (wave-parallel weights) --
__global__ __launch_bounds__(256) void k_agg4(
    const ushort* __restrict__ hbuf, const int2* __restrict__ epk,
    const int* __restrict__ deg, const float* __restrict__ a_s,
    const float* __restrict__ a_d, const float* __restrict__ wed,
    const float* __restrict__ bias, const float* __restrict__ bng,
    const float* __restrict__ bnb, const float* __restrict__ bnm,
    const float* __restrict__ bnv, ushort* __restrict__ xout) {
  __shared__ float lds_w[4][kMD][4];   // 4 KB: weight per (slot, h)
  __shared__ int   lds_s[4][kMD];      // 1 KB: src per slot
  __shared__ float lds_m[4][4][2];     // winv, selfw per h
  int tid = threadIdx.x;
  int w = tid >> 6, lane = tid & 63;
  int d = blockIdx.x * 4 + w;
  const int2* rp = &epk[(size_t)d * kMD];
  int dgt = deg[d];
  int dg = min(dgt, kMD);

  // ---- phase 1: lane = (slot0, h1); each exp computed once per (edge, head)
  int h1 = lane & 3, slot0 = lane >> 2;
  float adh1 = a_d[d * 4 + h1];
  float wdh1 = wed[h1];
  float szp = 0.f, seap = 0.f;
  for (int t = 0; t < dg; t += 16) {
    int slot = t + slot0;
    float wv = 0.f, ev = 0.f;
    if (slot < dg) {
      int2 rec = rp[slot];
      ev = __int_as_float(rec.y);
      float asv = a_s[rec.x * 4 + h1];
      wv = __expf(lrelu(asv + adh1 + ev * wdh1));
      lds_w[w][slot][h1] = wv;
      if (h1 == 0) lds_s[w][slot] = rec.x;
    }
    szp += wv;
    seap += (h1 == 0) ? ev : 0.f;
  }
#pragma unroll
  for (int off = 4; off < 64; off <<= 1) {
    szp  += __shfl_xor(szp, off, 64);
    seap += __shfl_xor(seap, off, 64);
  }
  float sea = __shfl(seap, lane & 0x3C, 64);  // broadcast from h==0 lane of group
  float lea = sea / fmaxf((float)dgt, 1.f);
  float selfw1 = __expf(lrelu(a_s[d * 4 + h1] + adh1 + lea * wdh1));
  float szh = szp + selfw1;
  if (slot0 == 0) {
    lds_m[w][h1][0] = 1.f / (szh + 1e-16f);
    lds_m[w][h1][1] = selfw1;
  }

  // ---- phase 2: gather + weighted accumulate (weights/srcs from LDS)
  int h2 = lane >> 4;
  int c0 = lane * 4;
  ushort4 vself = *(const ushort4*)&hbuf[(size_t)d * 256 + c0];  // hoisted
  float a0 = 0.f, a1 = 0.f, a2 = 0.f, a3 = 0.f;
  int k = 0;
  for (; k + 16 <= dg; k += 16) {
    int s16[16]; float w16[16];
#pragma unroll
    for (int j = 0; j < 16; j++) {
      s16[j] = lds_s[w][k + j];
      w16[j] = lds_w[w][k + j][h2];
    }
    ushort4 v16[16];
#pragma unroll
    for (int j = 0; j < 16; j++)
      v16[j] = *(const ushort4*)&hbuf[(size_t)s16[j] * 256 + c0];
#pragma unroll
    for (int j = 0; j < 16; j++) {
      a0 += w16[j] * bu(v16[j].x); a1 += w16[j] * bu(v16[j].y);
      a2 += w16[j] * bu(v16[j].z); a3 += w16[j] * bu(v16[j].w);
    }
  }
  for (; k + 8 <= dg; k += 8) {
    int s8[8]; float w8[8];
#pragma unroll
    for (int j = 0; j < 8; j++) {
      s8[j] = lds_s[w][k + j];
      w8[j] = lds_w[w][k + j][h2];
    }
    ushort4 v8[8];
#pragma unroll
    for (int j = 0; j < 8; j++)
      v8[j] = *(const ushort4*)&hbuf[(size_t)s8[j] * 256 + c0];
#pragma unroll
    for (int j = 0; j < 8; j++) {
      a0 += w8[j] * bu(v8[j].x); a1 += w8[j] * bu(v8[j].y);
      a2 += w8[j] * bu(v8[j].z); a3 += w8[j] * bu(v8[j].w);
    }
  }
  for (; k < dg; k++) {
    int s0 = lds_s[w][k];
    float w0 = lds_w[w][k][h2];
    ushort4 v0 = *(const ushort4*)&hbuf[(size_t)s0 * 256 + c0];
    a0 += w0 * bu(v0.x); a1 += w0 * bu(v0.y);
    a2 += w0 * bu(v0.z); a3 += w0 * bu(v0.w);
  }
  // self-loop
  float winv = lds_m[w][h2][0];
  float sw   = lds_m[w][h2][1];
  a0 += sw * bu(vself.x); a1 += sw * bu(vself.y);
  a2 += sw * bu(vself.z); a3 += sw * bu(vself.w);

  float4 bi = *(const float4*)&bias[c0];
  a0 = a0 * winv + bi.x; a1 = a1 * winv + bi.y;
  a2 = a2 * winv + bi.z; a3 = a3 * winv + bi.w;
  float4 g4 = *(const float4*)&bng[c0], b4 = *(const float4*)&bnb[c0];
  float4 m4 = *(const float4*)&bnm[c0], v4 = *(const float4*)&bnv[c0];
  a0 = fmaxf((a0 - m4.x) * rsqrtf(v4.x + BN_EPS_) * g4.x + b4.x, 0.f);
  a1 = fmaxf((a1 - m4.y) * rsqrtf(v4.y + BN_EPS_) * g4.y + b4.y, 0.f);
  a2 = fmaxf((a2 - m4.z) * rsqrtf(v4.z + BN_EPS_) * g4.z + b4.z, 0.f);
  a3 = fmaxf((a3 - m4.w) * rsqrtf(v4.w + BN_EPS_) * g4.w + b4.w, 0.f);
  ushort4 o = make_ushort4(f2u(a0), f2u(a1), f2u(a2), f2u(a3));
  *(ushort4*)&xout[(size_t)d * 256 + c0] = o;
}

// ---- final agg (H=1, 64 ch) + fused mean-pool + last-block MLP head --------
// All 4 dsts in a block share one graph (200 % 4 == 0 -> 50 blocks/graph).
__global__ __launch_bounds__(256) void k_agg1(
    const ushort* __restrict__ hbuf, const int2* __restrict__ epk,
    const int* __restrict__ deg, const float* __restrict__ a_s,
    const float* __restrict__ a_d, const float* __restrict__ wed,
    float* __restrict__ gsum, int* __restrict__ ticket,
    const float* __restrict__ bias,
    const float* __restrict__ cw1, const float* __restrict__ cb1,
    const float* __restrict__ cw2, const float* __restrict__ cb2,
    float* __restrict__ out) {
  __shared__ float lds_w[4][kMD];
  __shared__ int   lds_s[4][kMD];
  __shared__ float part[4][64];
  int tid = threadIdx.x;
  int w = tid >> 6, lane = tid & 63;
  int d = blockIdx.x * 4 + w;
  const int2* rp = &epk[(size_t)d * kMD];
  int dgt = deg[d];
  int dg = min(dgt, kMD);
  float adh = a_d[d];
  float wdh = wed[0];

  // phase 1: lane = slot (kMD == 64 -> single pass)
  float wv = 0.f, ev = 0.f;
  if (lane < dg) {
    int2 rec = rp[lane];
    ev = __int_as_float(rec.y);
    wv = __expf(lrelu(a_s[rec.x] + adh + ev * wdh));
    lds_w[w][lane] = wv;
    lds_s[w][lane] = rec.x;
  }
  float szp = wv, seap = ev;
#pragma unroll
  for (int off = 1; off < 64; off <<= 1) {
    szp  += __shfl_xor(szp, off, 64);
    seap += __shfl_xor(seap, off, 64);
  }
  float lea = seap / fmaxf((float)dgt, 1.f);
  float selfw = __expf(lrelu(a_s[d] + adh + lea * wdh));
  float winv = 1.f / (szp + selfw + 1e-16f);

  // phase 2
  float vselff = bu(hbuf[(size_t)d * 64 + lane]);  // hoisted
  float acc = 0.f;
  int k = 0;
  for (; k + 16 <= dg; k += 16) {
    int s16[16]; float w16[16];
#pragma unroll
    for (int j = 0; j < 16; j++) {
      s16[j] = lds_s[w][k + j];
      w16[j] = lds_w[w][k + j];
    }
    ushort v16[16];
#pragma unroll
    for (int j = 0; j < 16; j++) v16[j] = hbuf[(size_t)s16[j] * 64 + lane];
#pragma unroll
    for (int j = 0; j < 16; j++) acc += w16[j] * bu(v16[j]);
  }
  for (; k + 8 <= dg; k += 8) {
    int s8[8]; float w8[8];
#pragma unroll
    for (int j = 0; j < 8; j++) {
      s8[j] = lds_s[w][k + j];
      w8[j] = lds_w[w][k + j];
    }
    ushort v8[8];
#pragma unroll
    for (int j = 0; j < 8; j++) v8[j] = hbuf[(size_t)s8[j] * 64 + lane];
#pragma unroll
    for (int j = 0; j < 8; j++) acc += w8[j] * bu(v8[j]);
  }
  for (; k < dg; k++) {
    acc += lds_w[w][k] * bu(hbuf[(size_t)lds_s[w][k] * 64 + lane]);
  }
  acc += selfw * vselff;
  acc = acc * winv;                 // node value sans bias (bias added in head)

  part[w][lane] = acc;
  __syncthreads();
  if (w == 0) {
    float s = (part[0][lane] + part[1][lane]) + (part[2][lane] + part[3][lane]);
    int g = (blockIdx.x * 4) / kNPG;
    atomicAdd(&gsum[g * 64 + lane], s);
  }

  // ---- last block computes the MLP head for all graphs (saves a launch) ----
  __threadfence();
  __shared__ int lastFlag;
  if (tid == 0) lastFlag = (atomicAdd(ticket, 1) == (int)gridDim.x - 1) ? 1 : 0;
  __syncthreads();
  if (!lastFlag) return;
  __shared__ float gbl[4][64], hbl[4][64];
  for (int g0 = 0; g0 < kG; g0 += 4) {
    int g = g0 + w;
    // coherent read of cross-XCD atomic sums
    float gv = atomicAdd(&gsum[g * 64 + lane], 0.f) * (1.f / kNPG) + bias[lane];
    gbl[w][lane] = gv;
    __syncthreads();
    float s = cb1[lane];
#pragma unroll 8
    for (int i = 0; i < 64; i++) s += gbl[w][i] * cw1[i * 64 + lane];
    s = 0.5f * s * (1.f + erff(s * 0.70710678118654752f));  // exact GELU
    hbl[w][lane] = s;
    __syncthreads();
    if (lane < 2) {
      float o = cb2[lane];
      for (int i = 0; i < 64; i++) o += hbl[w][i] * cw2[i * 2 + lane];
      out[g * 2 + lane] = o;
    }
    __syncthreads();
  }
}

// ---------------- launch ----------------

extern "C" void kernel_launch(void* const* d_in, const int* in_sizes, int n_in,
                              void* d_out, int out_size, void* d_ws, size_t ws_size,
                              hipStream_t stream) {
  (void)in_sizes; (void)n_in; (void)out_size; (void)ws_size;
  const float* x  = (const float*)d_in[0];
  const int* ei   = (const int*)d_in[1];
  const float* ea = (const float*)d_in[2];
  const float *W[3], *as_[3], *ad_[3], *We[3], *ae[3], *bi[3];
  for (int l = 0; l < 3; l++) {
    W[l]   = (const float*)d_in[4 + l * 6 + 0];
    as_[l] = (const float*)d_in[4 + l * 6 + 1];
    ad_[l] = (const float*)d_in[4 + l * 6 + 2];
    We[l]  = (const float*)d_in[4 + l * 6 + 3];
    ae[l]  = (const float*)d_in[4 + l * 6 + 4];
    bi[l]  = (const float*)d_in[4 + l * 6 + 5];
  }
  const float* bng = (const float*)d_in[22];
  const float* bnb = (const float*)d_in[23];
  const float* bnm = (const float*)d_in[24];
  const float* bnv = (const float*)d_in[25];
  const float* cw1 = (const float*)d_in[26];
  const float* cb1 = (const float*)d_in[27];
  const float* cw2 = (const float*)d_in[28];
  const float* cb2 = (const float*)d_in[29];

  char* p = (char*)d_ws;
  auto alloc = [&](size_t bytes) -> void* {
    void* r = (void*)p;
    p += (bytes + 255) & ~(size_t)255;
    return r;
  };
  ushort* x2b   = (ushort*)alloc((size_t)kN * kK0 * 2);
  ushort* hbufb = (ushort*)alloc((size_t)kN * 256 * 2);
  ushort* xbA   = (ushort*)alloc((size_t)kN * 256 * 2);
  ushort* xbB   = (ushort*)alloc((size_t)kN * 256 * 2);
  ushort* Wt0   = (ushort*)alloc((size_t)kK0 * 256 * 2);
  ushort* Wt1   = (ushort*)alloc((size_t)256 * 256 * 2);
  ushort* Wt2   = (ushort*)alloc((size_t)256 * 64 * 2);
  float* a_s    = (float*)alloc((size_t)kN * 4 * 4);
  float* a_d    = (float*)alloc((size_t)kN * 4 * 4);
  int2* epk     = (int2*)alloc((size_t)kN * kMD * 8);  // 13.1 MB padded CSR
  float* wed    = (float*)alloc(256);
  int* deg      = (int*)alloc((size_t)kN * 4);         // 102400 B (256-mult)
  float* gsum   = (float*)alloc((size_t)kG * 64 * 4);  // 32768 B (256-mult)
  int* ticket   = (int*)alloc(256);                    // contiguous after gsum

  // 0: zero degree counters + graph accumulators + ticket in one memset
  hipMemsetAsync(deg, 0, (size_t)kN * 4 + (size_t)kG * 64 * 4 + 256, stream);
  // 1: fused prep (prep_x | Wt + wedot | per-edge degree + scatter | K-pads)
  k_pre<<<5000 + 2929, 256, 0, stream>>>(
      x, x2b, W[0], Wt0, W[1], Wt1, W[2], Wt2, We[0], ae[0], We[1], ae[1],
      We[2], ae[2], wed, ei, ea, epk, deg);
  // 2: layer-0 GEMM (K=448 padded)
  dim3 gg64m(1, kN / 64);
  k_gemm_f<256, 64><<<gg64m, 256, 0, stream>>>(x2b, Wt0, hbufb, as_[0], ad_[0],
                                               a_s, a_d, kK0);
  // 3: agg layer0
  k_agg4<<<kN / 4, 256, 0, stream>>>(hbufb, epk, deg, a_s, a_d,
                                     &wed[0], bi[0], bng, bnb, bnm, bnv, xbA);
  // 4: gemm layer1
  k_gemm_f<256, 64><<<gg64m, 256, 0, stream>>>(xbA, Wt1, hbufb, as_[1], ad_[1],
                                               a_s, a_d, 256);
  // 5: agg layer1
  k_agg4<<<kN / 4, 256, 0, stream>>>(hbufb, epk, deg, a_s, a_d,
                                     &wed[4], bi[1], bng, bnb, bnm, bnv, xbB);
  // 6: gemm layer2
  dim3 gg64(1, kN / 64);
  k_gemm_f<64, 64><<<gg64, 256, 0, stream>>>(xbB, Wt2, hbufb, as_[2], ad_[2],
                                             a_s, a_d, 256);
  // 7: agg layer2 (H=1) + fused mean-pool + last-block MLP head
  k_agg1<<<kN / 4, 256, 0, stream>>>(hbufb, epk, deg, a_s, a_d, &wed[8],
                                     gsum, ticket, bi[2], cw1, cb1, cw2, cb2,
                                     (float*)d_out);
}

// Round 9
// 319.615 us; speedup vs baseline: 2.4291x; 2.4291x over previous
//
#include <hip/hip_runtime.h>
#include <hip/hip_bf16.h>

static const int kN  = 25600;   // nodes
static const int kE  = 409600;  // edges
static const int kG  = 128;     // graphs
static const int kNPG = 200;    // nodes per graph
static const int kIN = 200;     // raw feat dim
static const int kIN2 = 400;    // after nan-mask concat
static const int kK0 = 448;     // layer-0 K padded to 64-multiple for global_load_lds
static const int kMD = 64;      // padded CSR max degree (mean 16, sigma 4 -> 12 sigma)
#define BN_EPS_ 1e-5f

typedef __attribute__((ext_vector_type(8))) short short8;
typedef __attribute__((ext_vector_type(4))) ushort us4;
typedef __attribute__((ext_vector_type(4))) float f32x4;

__device__ __forceinline__ float bu(ushort u) {
  union { float f; unsigned u32; } x; x.u32 = ((unsigned)u) << 16; return x.f;
}
__device__ __forceinline__ ushort f2u(float v) {
  __hip_bfloat16 t = __float2bfloat16(v);  // RN
  return *(ushort*)&t;
}
__device__ __forceinline__ float wredSum(float v) {
#pragma unroll
  for (int off = 1; off < 64; off <<= 1) v += __shfl_xor(v, off, 64);
  return v;
}
__device__ __forceinline__ float lrelu(float a) { return (a > 0.f) ? a : 0.2f * a; }

// async global->LDS, 16B per lane; dest = wave-uniform base + lane*16
#define GLOAD16(g, l) __builtin_amdgcn_global_load_lds( \
    (const __attribute__((address_space(1))) unsigned int*)(g), \
    (__attribute__((address_space(3))) unsigned int*)(l), 16, 0, 0)

// ---- fused prep: prep_x | Wt + wedot | edge-degree + direct scatter | pads --
// pb regions: [0,720) Wt, [720,723) wedot, [723,2323) edges, [2323,2929) pads
__global__ void k_pre(const float* __restrict__ x, ushort* __restrict__ x2,
                      const float* __restrict__ W0, ushort* __restrict__ Wt0,
                      const float* __restrict__ W1, ushort* __restrict__ Wt1,
                      const float* __restrict__ W2, ushort* __restrict__ Wt2,
                      const float* __restrict__ We0, const float* __restrict__ ae0,
                      const float* __restrict__ We1, const float* __restrict__ ae1,
                      const float* __restrict__ We2, const float* __restrict__ ae2,
                      float* __restrict__ wed,
                      const int* __restrict__ ei, const float* __restrict__ ea,
                      int2* __restrict__ epk, int* __restrict__ deg) {
  int b = blockIdx.x, tid = threadIdx.x;
  if (b < 5000) {
    int i4 = (b * 256 + tid) * 4;          // kIN=200 divisible by 4
    int n = i4 / kIN, j = i4 - n * kIN;
    float4 v = *(const float4*)&x[i4];
    ushort o0[4], o1[4];
    float vv[4] = {v.x, v.y, v.z, v.w};
#pragma unroll
    for (int q = 0; q < 4; q++) {
      bool bad = (vv[q] != vv[q]);
      o0[q] = f2u(bad ? 0.f : vv[q]);
      o1[q] = f2u(bad ? 1.f : 0.f);
    }
    *(us4*)&x2[(size_t)n * kK0 + j] = *(us4*)o0;
    *(us4*)&x2[(size_t)n * kK0 + kIN + j] = *(us4*)o1;
    return;
  }
  int pb = b - 5000;
  if (pb >= 2323) {
    // zero the K-pad [400,448) of x2 rows and Wt0 rows (16B stores)
    int idx = (pb - 2323) * 256 + tid;
    short8 z = {0, 0, 0, 0, 0, 0, 0, 0};
    if (idx < 153600) {
      int row = idx / 6, c = idx - row * 6;
      *(short8*)&x2[(size_t)row * kK0 + kIN2 + c * 8] = z;
    } else {
      int j = idx - 153600;
      if (j < 1536) {
        int row = j / 6, c = j - row * 6;
        *(short8*)&Wt0[(size_t)row * kK0 + kIN2 + c * 8] = z;
      }
    }
    return;
  }
  if (pb >= 723) {
    // per-edge: degree count + direct scatter into padded CSR (deg pre-zeroed)
    int e = (pb - 723) * 256 + tid;
    int d = ei[kE + e];
    int s = ei[e];
    float v = ea[e];
    if (v != v) v = 0.f;
    int slot = atomicAdd(&deg[d], 1);
    if (slot < kMD) {
      int2 rec; rec.x = s; rec.y = __float_as_int(v);
      epk[(size_t)d * kMD + slot] = rec;
    }
    return;
  }
  if (pb >= 720) {
    int l = pb - 720;
    const float* We = (l == 0) ? We0 : (l == 1) ? We1 : We2;
    const float* ae = (l == 0) ? ae0 : (l == 1) ? ae1 : ae2;
    int n = (l == 2) ? 64 : 256;
    float v = (tid < n) ? We[tid] * ae[tid] : 0.f;
    v = wredSum(v);
    if ((tid & 63) == 0 && tid < n) wed[l * 4 + (tid >> 6)] = v;
    return;
  }
  int i = pb * 256 + tid;
  if (i < 102400) {
    int n = i / kIN2, k = i - n * kIN2;            // N=256, K=400 (stride 448)
    Wt0[(size_t)n * kK0 + k] = f2u(W0[(size_t)k * 256 + n]);
  } else if (i < 102400 + 65536) {
    int j = i - 102400;
    int n = j >> 8, k = j & 255;                   // N=256, K=256
    Wt1[(size_t)n * 256 + k] = f2u(W1[(size_t)k * 256 + n]);
  } else {
    int j = i - 102400 - 65536;
    int n = j >> 8, k = j & 255;                   // N=64, K=256
    Wt2[(size_t)n * 256 + k] = f2u(W2[(size_t)k * 64 + n]);
  }
}

// ---------------- MFMA GEMM + fused attention dots --------------------------
// AHM=false: A row-major [rows][K].  AHM=true: A head-major [K/64][kN][64]
// (K-tile kt reads head plane kt/64 -- tile size 64 == head block).
// BN==256: C written head-major [4][kN][64], a_s/a_d head-major [4][kN].
// BN==64:  C written [rows][64], a_s/a_d [kN].
// LDS staging via global_load_lds, XOR swizzle on the SOURCE address.
template <int BN, int MT, bool AHM>
__global__ __launch_bounds__(256) void k_gemm_f(const ushort* __restrict__ A,
                                                const ushort* __restrict__ Bt,
                                                ushort* __restrict__ C,
                                                const float* __restrict__ as_g,
                                                const float* __restrict__ ad_g,
                                                float* __restrict__ a_sg,
                                                float* __restrict__ a_dg, int K) {
  constexpr int MI = (BN == 256) ? (MT / 16) : 1;
  __shared__ ushort As[MT * 64];
  __shared__ ushort Bs[BN * 64];
  int tid = threadIdx.x;
  int lane = tid & 63, w = tid >> 6;
  int l15 = lane & 15, l4 = lane >> 4;
  int row0 = blockIdx.y * MT;
  int wr = (BN == 256) ? 0 : (w * 16);
  int wc = (BN == 256) ? (w * 64) : 0;
  f32x4 acc[MI][4] = {};
  int srow = lane >> 3;   // row within 8-row staging group
  int schunk = lane & 7;  // 16B chunk within 128B row

  for (int kt = 0; kt < K; kt += 64) {
    __syncthreads();
#pragma unroll
    for (int i = 0; i < MT / 32; i++) {
      int ra = w * (MT / 4) + i * 8;
      int r = ra + srow;
      const ushort* ap = AHM
          ? &A[(size_t)(kt >> 6) * ((size_t)kN * 64) + (size_t)(row0 + r) * 64 +
               ((schunk ^ (r & 7)) * 8)]
          : &A[(size_t)(row0 + r) * K + kt + ((schunk ^ (r & 7)) * 8)];
      GLOAD16(ap, &As[ra * 64]);
    }
#pragma unroll
    for (int i = 0; i < BN / 32; i++) {
      int rb = w * (BN / 4) + i * 8;
      int r = rb + srow;
      GLOAD16(&Bt[(size_t)r * K + kt + ((schunk ^ (r & 7)) * 8)],
              &Bs[rb * 64]);
    }
    __syncthreads();  // drains vmcnt before barrier
#pragma unroll
    for (int kk = 0; kk < 2; kk++) {
      short8 af[MI], bf[4];
#pragma unroll
      for (int mi = 0; mi < MI; mi++) {
        int r = wr + mi * 16 + l15;
        af[mi] = *(const short8*)&As[r * 64 + ((kk * 32 + l4 * 8) ^ ((r & 7) * 8))];
      }
#pragma unroll
      for (int ni = 0; ni < 4; ni++) {
        int r = wc + ni * 16 + l15;
        bf[ni] = *(const short8*)&Bs[r * 64 + ((kk * 32 + l4 * 8) ^ ((r & 7) * 8))];
      }
#pragma unroll
      for (int mi = 0; mi < MI; mi++)
#pragma unroll
        for (int ni = 0; ni < 4; ni++)
          acc[mi][ni] = __builtin_amdgcn_mfma_f32_16x16x32_bf16(af[mi], bf[ni],
                                                                acc[mi][ni], 0, 0, 0);
    }
  }
#pragma unroll
  for (int mi = 0; mi < MI; mi++) {
    int rbase = row0 + wr + mi * 16 + l4 * 4;
#pragma unroll
    for (int ni = 0; ni < 4; ni++) {
      int col = wc + ni * 16 + l15;
#pragma unroll
      for (int r = 0; r < 4; r++) {
        size_t caddr = (BN == 256)
            ? ((size_t)w * ((size_t)kN * 64) + (size_t)(rbase + r) * 64 + (col & 63))
            : ((size_t)(rbase + r) * BN + col);
        C[caddr] = f2u(acc[mi][ni][r]);
      }
    }
  }
  float asv[4], adv[4];
#pragma unroll
  for (int ni = 0; ni < 4; ni++) {
    asv[ni] = as_g[wc + ni * 16 + l15];
    adv[ni] = ad_g[wc + ni * 16 + l15];
  }
#pragma unroll
  for (int mi = 0; mi < MI; mi++) {
#pragma unroll
    for (int r = 0; r < 4; r++) {
      float ps = 0.f, pd = 0.f;
#pragma unroll
      for (int ni = 0; ni < 4; ni++) {
        ps += acc[mi][ni][r] * asv[ni];
        pd += acc[mi][ni][r] * adv[ni];
      }
#pragma unroll
      for (int off = 1; off < 16; off <<= 1) {
        ps += __shfl_xor(ps, off, 64);
        pd += __shfl_xor(pd, off, 64);
      }
      if (l15 == 0) {
        int row = row0 + wr + mi * 16 + l4 * 4 + r;
        size_t aaddr = (BN == 256) ? ((size_t)w * kN + row) : (size_t)row;
        a_sg[aaddr] = ps;
        a_dg[aaddr] = pd;
      }
    }
  }
}

// ---- fused logit+softmax+aggregate: 16 dsts x 1 head per block -------------
// hbuf/xout head-major [4][kN][64]; a_s/a_d [4][kN].
// grid 6400: head = (bid&7)>>1 (XCD-pinned 3.2 MB L2 slice).
// Phase 1: 256 thr = (dst16, slot16), full lane efficiency, exp once/(edge,head).
// Phase 2: wave = 4 dsts; lanes (e4, c16) -> 512 B gathered per instruction.
__global__ __launch_bounds__(256) void k_agg4(
    const ushort* __restrict__ hbuf, const int2* __restrict__ epk,
    const int* __restrict__ deg, const float* __restrict__ a_s,
    const float* __restrict__ a_d, const float* __restrict__ wed,
    const float* __restrict__ bias, const float* __restrict__ bng,
    const float* __restrict__ bnb, const float* __restrict__ bnm,
    const float* __restrict__ bnv, ushort* __restrict__ xout) {
  __shared__ float lds_w[16][kMD];   // 4 KB
  __shared__ int   lds_s[16][kMD];   // 4 KB
  __shared__ float lds_m[16][2];     // winv, selfw per dst
  int tid = threadIdx.x;
  int bid = blockIdx.x;
  int r8 = bid & 7;
  int head = r8 >> 1;
  int dgroup = (r8 & 1) * 800 + (bid >> 3);   // 0..1599
  int dbase = dgroup * 16;
  const ushort* hb = hbuf + (size_t)head * kN * 64;
  const float* asg = a_s + (size_t)head * kN;
  float wdh = wed[head];

  // ---- phase 1: tid = (dst16, slot16)
  {
    int di = tid >> 4, slot0 = tid & 15;
    int d = dbase + di;
    int dgt = deg[d];
    int dg = min(dgt, kMD);
    float adh = a_d[(size_t)head * kN + d];
    const int2* rp = &epk[(size_t)d * kMD];
    float szp = 0.f, seap = 0.f;
    for (int t = slot0; t < dg; t += 16) {
      int2 rec = rp[t];
      float ev = __int_as_float(rec.y);
      float wv = __expf(lrelu(asg[rec.x] + adh + ev * wdh));
      lds_w[di][t] = wv;
      lds_s[di][t] = rec.x;
      szp += wv;
      seap += ev;
    }
#pragma unroll
    for (int off = 1; off < 16; off <<= 1) {
      szp  += __shfl_xor(szp, off, 64);
      seap += __shfl_xor(seap, off, 64);
    }
    if (slot0 == 0) {
      float lea = seap / fmaxf((float)dgt, 1.f);
      float selfw = __expf(lrelu(asg[d] + adh + lea * wdh));
      lds_m[di][0] = 1.f / (szp + selfw + 1e-16f);
      lds_m[di][1] = selfw;
    }
  }
  __syncthreads();

  // ---- phase 2: wave w handles dsts w*4..w*4+3; lanes (e4, c16)
  int w = tid >> 6, lane = tid & 63;
  int e4 = lane >> 4;        // edge sub-slot
  int c4 = (lane & 15) * 4;  // channel quad base
#pragma unroll
  for (int j = 0; j < 4; j++) {
    int di = w * 4 + j;
    int d = dbase + di;
    int dg = min(deg[d], kMD);
    float a0 = 0.f, a1 = 0.f, a2 = 0.f, a3 = 0.f;
    int k = 0;
    for (; k + 16 <= dg; k += 16) {
      int s4[4]; float w4[4];
#pragma unroll
      for (int q = 0; q < 4; q++) {
        s4[q] = lds_s[di][k + q * 4 + e4];
        w4[q] = lds_w[di][k + q * 4 + e4];
      }
      ushort4 v4[4];
#pragma unroll
      for (int q = 0; q < 4; q++)
        v4[q] = *(const ushort4*)&hb[(size_t)s4[q] * 64 + c4];
#pragma unroll
      for (int q = 0; q < 4; q++) {
        a0 += w4[q] * bu(v4[q].x); a1 += w4[q] * bu(v4[q].y);
        a2 += w4[q] * bu(v4[q].z); a3 += w4[q] * bu(v4[q].w);
      }
    }
    for (; k + 4 <= dg; k += 4) {
      int s0 = lds_s[di][k + e4];
      float w0 = lds_w[di][k + e4];
      ushort4 v0 = *(const ushort4*)&hb[(size_t)s0 * 64 + c4];
      a0 += w0 * bu(v0.x); a1 += w0 * bu(v0.y);
      a2 += w0 * bu(v0.z); a3 += w0 * bu(v0.w);
    }
    if (k + e4 < dg) {
      int s0 = lds_s[di][k + e4];
      float w0 = lds_w[di][k + e4];
      ushort4 v0 = *(const ushort4*)&hb[(size_t)s0 * 64 + c4];
      a0 += w0 * bu(v0.x); a1 += w0 * bu(v0.y);
      a2 += w0 * bu(v0.z); a3 += w0 * bu(v0.w);
    }
    // fold 4 edge-partials (lane bits 4,5)
    a0 += __shfl_xor(a0, 16, 64); a0 += __shfl_xor(a0, 32, 64);
    a1 += __shfl_xor(a1, 16, 64); a1 += __shfl_xor(a1, 32, 64);
    a2 += __shfl_xor(a2, 16, 64); a2 += __shfl_xor(a2, 32, 64);
    a3 += __shfl_xor(a3, 16, 64); a3 += __shfl_xor(a3, 32, 64);

    if (e4 == 0) {
      float winv = lds_m[di][0];
      float sw   = lds_m[di][1];
      ushort4 vs = *(const ushort4*)&hb[(size_t)d * 64 + c4];
      a0 += sw * bu(vs.x); a1 += sw * bu(vs.y);
      a2 += sw * bu(vs.z); a3 += sw * bu(vs.w);
      int c = head * 64 + c4;
      float4 bi = *(const float4*)&bias[c];
      a0 = a0 * winv + bi.x; a1 = a1 * winv + bi.y;
      a2 = a2 * winv + bi.z; a3 = a3 * winv + bi.w;
      float4 g4 = *(const float4*)&bng[c], b4 = *(const float4*)&bnb[c];
      float4 m4 = *(const float4*)&bnm[c], v4 = *(const float4*)&bnv[c];
      a0 = fmaxf((a0 - m4.x) * rsqrtf(v4.x + BN_EPS_) * g4.x + b4.x, 0.f);
      a1 = fmaxf((a1 - m4.y) * rsqrtf(v4.y + BN_EPS_) * g4.y + b4.y, 0.f);
      a2 = fmaxf((a2 - m4.z) * rsqrtf(v4.z + BN_EPS_) * g4.z + b4.z, 0.f);
      a3 = fmaxf((a3 - m4.w) * rsqrtf(v4.w + BN_EPS_) * g4.w + b4.w, 0.f);
      ushort4 o = make_ushort4(f2u(a0), f2u(a1), f2u(a2), f2u(a3));
      *(ushort4*)&xout[(size_t)head * kN * 64 + (size_t)d * 64 + c4] = o;
    }
  }
}

// ---- final agg (H=1, 64 ch) + fused per-graph mean-pool (atomics) ----------
// All 4 dsts in a block share one graph (200 % 4 == 0 -> 50 blocks/graph).
__global__ __launch_bounds__(256) void k_agg1(
    const ushort* __restrict__ hbuf, const int2* __restrict__ epk,
    const int* __restrict__ deg, const float* __restrict__ a_s,
    const float* __restrict__ a_d, const float* __restrict__ wed,
    float* __restrict__ gsum) {
  __shared__ float lds_w[4][kMD];
  __shared__ int   lds_s[4][kMD];
  __shared__ float part[4][64];
  int tid = threadIdx.x;
  int w = tid >> 6, lane = tid & 63;
  int d = blockIdx.x * 4 + w;
  const int2* rp = &epk[(size_t)d * kMD];
  int dgt = deg[d];
  int dg = min(dgt, kMD);
  float adh = a_d[d];
  float wdh = wed[0];

  // phase 1: lane = slot (kMD == 64 -> single pass)
  float wv = 0.f, ev = 0.f;
  if (lane < dg) {
    int2 rec = rp[lane];
    ev = __int_as_float(rec.y);
    wv = __expf(lrelu(a_s[rec.x] + adh + ev * wdh));
    lds_w[w][lane] = wv;
    lds_s[w][lane] = rec.x;
  }
  float szp = wv, seap = ev;
#pragma unroll
  for (int off = 1; off < 64; off <<= 1) {
    szp  += __shfl_xor(szp, off, 64);
    seap += __shfl_xor(seap, off, 64);
  }
  float lea = seap / fmaxf((float)dgt, 1.f);
  float selfw = __expf(lrelu(a_s[d] + adh + lea * wdh));
  float winv = 1.f / (szp + selfw + 1e-16f);

  // phase 2
  float vselff = bu(hbuf[(size_t)d * 64 + lane]);  // hoisted
  float acc = 0.f;
  int k = 0;
  for (; k + 16 <= dg; k += 16) {
    int s16[16]; float w16[16];
#pragma unroll
    for (int j = 0; j < 16; j++) {
      s16[j] = lds_s[w][k + j];
      w16[j] = lds_w[w][k + j];
    }
    ushort v16[16];
#pragma unroll
    for (int j = 0; j < 16; j++) v16[j] = hbuf[(size_t)s16[j] * 64 + lane];
#pragma unroll
    for (int j = 0; j < 16; j++) acc += w16[j] * bu(v16[j]);
  }
  for (; k + 8 <= dg; k += 8) {
    int s8[8]; float w8[8];
#pragma unroll
    for (int j = 0; j < 8; j++) {
      s8[j] = lds_s[w][k + j];
      w8[j] = lds_w[w][k + j];
    }
    ushort v8[8];
#pragma unroll
    for (int j = 0; j < 8; j++) v8[j] = hbuf[(size_t)s8[j] * 64 + lane];
#pragma unroll
    for (int j = 0; j < 8; j++) acc += w8[j] * bu(v8[j]);
  }
  for (; k < dg; k++) {
    acc += lds_w[w][k] * bu(hbuf[(size_t)lds_s[w][k] * 64 + lane]);
  }
  acc += selfw * vselff;
  acc = acc * winv;                 // node value sans bias (bias added in head)

  part[w][lane] = acc;
  __syncthreads();
  if (w == 0) {
    float s = (part[0][lane] + part[1][lane]) + (part[2][lane] + part[3][lane]);
    int g = (blockIdx.x * 4) / kNPG;
    atomicAdd(&gsum[g * 64 + lane], s);
  }
}

// ---------------- MLP head (pool sums precomputed in gsum) ----------------
__global__ void k_head(const float* __restrict__ gsum, const float* __restrict__ bias,
                       const float* __restrict__ cw1, const float* __restrict__ cb1,
                       const float* __restrict__ cw2, const float* __restrict__ cb2,
                       float* __restrict__ out) {
  __shared__ float gb[64], hb[64];
  int g = blockIdx.x, c = threadIdx.x;
  gb[c] = gsum[g * 64 + c] * (1.f / kNPG) + bias[c];
  __syncthreads();
  float s = cb1[c];
#pragma unroll 8
  for (int i = 0; i < 64; i++) s += gb[i] * cw1[i * 64 + c];
  s = 0.5f * s * (1.f + erff(s * 0.70710678118654752f));  // exact GELU
  hb[c] = s;
  __syncthreads();
  if (c < 2) {
    float o = cb2[c];
    for (int i = 0; i < 64; i++) o += hb[i] * cw2[i * 2 + c];
    out[g * 2 + c] = o;
  }
}

// ---------------- launch ----------------

extern "C" void kernel_launch(void* const* d_in, const int* in_sizes, int n_in,
                              void* d_out, int out_size, void* d_ws, size_t ws_size,
                              hipStream_t stream) {
  (void)in_sizes; (void)n_in; (void)out_size; (void)ws_size;
  const float* x  = (const float*)d_in[0];
  const int* ei   = (const int*)d_in[1];
  const float* ea = (const float*)d_in[2];
  const float *W[3], *as_[3], *ad_[3], *We[3], *ae[3], *bi[3];
  for (int l = 0; l < 3; l++) {
    W[l]   = (const float*)d_in[4 + l * 6 + 0];
    as_[l] = (const float*)d_in[4 + l * 6 + 1];
    ad_[l] = (const float*)d_in[4 + l * 6 + 2];
    We[l]  = (const float*)d_in[4 + l * 6 + 3];
    ae[l]  = (const float*)d_in[4 + l * 6 + 4];
    bi[l]  = (const float*)d_in[4 + l * 6 + 5];
  }
  const float* bng = (const float*)d_in[22];
  const float* bnb = (const float*)d_in[23];
  const float* bnm = (const float*)d_in[24];
  const float* bnv = (const float*)d_in[25];
  const float* cw1 = (const float*)d_in[26];
  const float* cb1 = (const float*)d_in[27];
  const float* cw2 = (const float*)d_in[28];
  const float* cb2 = (const float*)d_in[29];

  char* p = (char*)d_ws;
  auto alloc = [&](size_t bytes) -> void* {
    void* r = (void*)p;
    p += (bytes + 255) & ~(size_t)255;
    return r;
  };
  ushort* x2b   = (ushort*)alloc((size_t)kN * kK0 * 2);
  ushort* hbufb = (ushort*)alloc((size_t)kN * 256 * 2);   // [4][kN][64] for H=4
  ushort* xbA   = (ushort*)alloc((size_t)kN * 256 * 2);   // [4][kN][64]
  ushort* xbB   = (ushort*)alloc((size_t)kN * 256 * 2);   // [4][kN][64]
  ushort* Wt0   = (ushort*)alloc((size_t)kK0 * 256 * 2);
  ushort* Wt1   = (ushort*)alloc((size_t)256 * 256 * 2);
  ushort* Wt2   = (ushort*)alloc((size_t)256 * 64 * 2);
  float* a_s    = (float*)alloc((size_t)kN * 4 * 4);      // [4][kN]
  float* a_d    = (float*)alloc((size_t)kN * 4 * 4);      // [4][kN]
  int2* epk     = (int2*)alloc((size_t)kN * kMD * 8);     // 13.1 MB padded CSR
  float* wed    = (float*)alloc(256);
  int* deg      = (int*)alloc((size_t)kN * 4);            // 102400 B (256-mult)
  float* gsum   = (float*)alloc((size_t)kG * 64 * 4);     // contiguous after deg

  // 0: zero degree counters + graph accumulators in one memset
  hipMemsetAsync(deg, 0, (size_t)kN * 4 + (size_t)kG * 64 * 4, stream);
  // 1: fused prep (prep_x | Wt + wedot | per-edge degree + scatter | K-pads)
  k_pre<<<5000 + 2929, 256, 0, stream>>>(
      x, x2b, W[0], Wt0, W[1], Wt1, W[2], Wt2, We[0], ae[0], We[1], ae[1],
      We[2], ae[2], wed, ei, ea, epk, deg);
  // 2: layer-0 GEMM (K=448 padded, A row-major, C head-major)
  dim3 gg64m(1, kN / 64);
  k_gemm_f<256, 64, false><<<gg64m, 256, 0, stream>>>(
      x2b, Wt0, hbufb, as_[0], ad_[0], a_s, a_d, kK0);
  // 3: agg layer0 (16 dsts x 1 head per block, XCD head-pinned)
  k_agg4<<<6400, 256, 0, stream>>>(hbufb, epk, deg, a_s, a_d,
                                   &wed[0], bi[0], bng, bnb, bnm, bnv, xbA);
  // 4: gemm layer1 (A head-major)
  k_gemm_f<256, 64, true><<<gg64m, 256, 0, stream>>>(
      xbA, Wt1, hbufb, as_[1], ad_[1], a_s, a_d, 256);
  // 5: agg layer1
  k_agg4<<<6400, 256, 0, stream>>>(hbufb, epk, deg, a_s, a_d,
                                   &wed[4], bi[1], bng, bnb, bnm, bnv, xbB);
  // 6: gemm layer2 (A head-major, C [N][64])
  dim3 gg64(1, kN / 64);
  k_gemm_f<64, 64, true><<<gg64, 256, 0, stream>>>(
      xbB, Wt2, hbufb, as_[2], ad_[2], a_s, a_d, 256);
  // 7: agg layer2 (H=1) + fused mean-pool
  k_agg1<<<kN / 4, 256, 0, stream>>>(hbufb, epk, deg, a_s, a_d, &wed[8], gsum);
  // 8: MLP head
  k_head<<<kG, 64, 0, stream>>>(gsum, bi[2], cw1, cb1, cw2, cb2, (float*)d_out);
}

// Round 10
// 288.781 us; speedup vs baseline: 2.6885x; 1.1068x over previous
//
#include <hip/hip_runtime.h>
#include <hip/hip_bf16.h>

static const int kN  = 25600;   // nodes
static const int kE  = 409600;  // edges
static const int kG  = 128;     // graphs
static const int kNPG = 200;    // nodes per graph
static const int kIN = 200;     // raw feat dim
static const int kIN2 = 400;    // after nan-mask concat
static const int kK0 = 448;     // layer-0 K padded to 64-multiple for global_load_lds
static const int kMD = 64;      // padded CSR max degree (mean 16, sigma 4 -> 12 sigma)
#define BN_EPS_ 1e-5f

typedef __attribute__((ext_vector_type(8))) short short8;
typedef __attribute__((ext_vector_type(4))) ushort us4;
typedef __attribute__((ext_vector_type(4))) float f32x4;

__device__ __forceinline__ float bu(ushort u) {
  union { float f; unsigned u32; } x; x.u32 = ((unsigned)u) << 16; return x.f;
}
__device__ __forceinline__ ushort f2u(float v) {
  __hip_bfloat16 t = __float2bfloat16(v);  // RN
  return *(ushort*)&t;
}
__device__ __forceinline__ float wredSum(float v) {
#pragma unroll
  for (int off = 1; off < 64; off <<= 1) v += __shfl_xor(v, off, 64);
  return v;
}
__device__ __forceinline__ float lrelu(float a) { return (a > 0.f) ? a : 0.2f * a; }

// async global->LDS, 16B per lane; dest = wave-uniform base + lane*16
#define GLOAD16(g, l) __builtin_amdgcn_global_load_lds( \
    (const __attribute__((address_space(1))) unsigned int*)(g), \
    (__attribute__((address_space(3))) unsigned int*)(l), 16, 0, 0)

// ---- fused prep: prep_x | Wt + wedot | edge-degree + direct scatter | pads --
// pb regions: [0,720) Wt, [720,723) wedot, [723,2323) edges, [2323,2929) pads
__global__ void k_pre(const float* __restrict__ x, ushort* __restrict__ x2,
                      const float* __restrict__ W0, ushort* __restrict__ Wt0,
                      const float* __restrict__ W1, ushort* __restrict__ Wt1,
                      const float* __restrict__ W2, ushort* __restrict__ Wt2,
                      const float* __restrict__ We0, const float* __restrict__ ae0,
                      const float* __restrict__ We1, const float* __restrict__ ae1,
                      const float* __restrict__ We2, const float* __restrict__ ae2,
                      float* __restrict__ wed,
                      const int* __restrict__ ei, const float* __restrict__ ea,
                      int2* __restrict__ epk, int* __restrict__ deg) {
  int b = blockIdx.x, tid = threadIdx.x;
  if (b < 5000) {
    int i4 = (b * 256 + tid) * 4;          // kIN=200 divisible by 4
    int n = i4 / kIN, j = i4 - n * kIN;
    float4 v = *(const float4*)&x[i4];
    ushort o0[4], o1[4];
    float vv[4] = {v.x, v.y, v.z, v.w};
#pragma unroll
    for (int q = 0; q < 4; q++) {
      bool bad = (vv[q] != vv[q]);
      o0[q] = f2u(bad ? 0.f : vv[q]);
      o1[q] = f2u(bad ? 1.f : 0.f);
    }
    *(us4*)&x2[(size_t)n * kK0 + j] = *(us4*)o0;
    *(us4*)&x2[(size_t)n * kK0 + kIN + j] = *(us4*)o1;
    return;
  }
  int pb = b - 5000;
  if (pb >= 2323) {
    // zero the K-pad [400,448) of x2 rows and Wt0 rows (16B stores)
    int idx = (pb - 2323) * 256 + tid;
    short8 z = {0, 0, 0, 0, 0, 0, 0, 0};
    if (idx < 153600) {
      int row = idx / 6, c = idx - row * 6;
      *(short8*)&x2[(size_t)row * kK0 + kIN2 + c * 8] = z;
    } else {
      int j = idx - 153600;
      if (j < 1536) {
        int row = j / 6, c = j - row * 6;
        *(short8*)&Wt0[(size_t)row * kK0 + kIN2 + c * 8] = z;
      }
    }
    return;
  }
  if (pb >= 723) {
    // per-edge: degree count + direct scatter into padded CSR (deg pre-zeroed)
    int e = (pb - 723) * 256 + tid;
    int d = ei[kE + e];
    int s = ei[e];
    float v = ea[e];
    if (v != v) v = 0.f;
    int slot = atomicAdd(&deg[d], 1);
    if (slot < kMD) {
      int2 rec; rec.x = s; rec.y = __float_as_int(v);
      epk[(size_t)d * kMD + slot] = rec;
    }
    return;
  }
  if (pb >= 720) {
    int l = pb - 720;
    const float* We = (l == 0) ? We0 : (l == 1) ? We1 : We2;
    const float* ae = (l == 0) ? ae0 : (l == 1) ? ae1 : ae2;
    int n = (l == 2) ? 64 : 256;
    float v = (tid < n) ? We[tid] * ae[tid] : 0.f;
    v = wredSum(v);
    if ((tid & 63) == 0 && tid < n) wed[l * 4 + (tid >> 6)] = v;
    return;
  }
  int i = pb * 256 + tid;
  if (i < 102400) {
    int n = i / kIN2, k = i - n * kIN2;            // N=256, K=400 (stride 448)
    Wt0[(size_t)n * kK0 + k] = f2u(W0[(size_t)k * 256 + n]);
  } else if (i < 102400 + 65536) {
    int j = i - 102400;
    int n = j >> 8, k = j & 255;                   // N=256, K=256
    Wt1[(size_t)n * 256 + k] = f2u(W1[(size_t)k * 256 + n]);
  } else {
    int j = i - 102400 - 65536;
    int n = j >> 8, k = j & 255;                   // N=64, K=256
    Wt2[(size_t)n * 256 + k] = f2u(W2[(size_t)k * 64 + n]);
  }
}

// ---------------- MFMA GEMM + fused attention dots --------------------------
// LDS staging via global_load_lds, XOR swizzle on the SOURCE address;
// linear LDS [rows][64], 16B chunk c of row r holds global chunk c^(r&7).
// K must be a multiple of 64.
template <int BN, int MT>
__global__ __launch_bounds__(256) void k_gemm_f(const ushort* __restrict__ A,
                                                const ushort* __restrict__ Bt,
                                                ushort* __restrict__ C,
                                                const float* __restrict__ as_g,
                                                const float* __restrict__ ad_g,
                                                float* __restrict__ a_sg,
                                                float* __restrict__ a_dg, int K) {
  constexpr int MI = (BN == 256) ? (MT / 16) : 1;
  constexpr int H = (BN == 256) ? 4 : 1;
  __shared__ ushort As[MT * 64];
  __shared__ ushort Bs[BN * 64];
  int tid = threadIdx.x;
  int lane = tid & 63, w = tid >> 6;
  int l15 = lane & 15, l4 = lane >> 4;
  int row0 = blockIdx.y * MT;
  int wr = (BN == 256) ? 0 : (w * 16);
  int wc = (BN == 256) ? (w * 64) : 0;
  f32x4 acc[MI][4] = {};
  int srow = lane >> 3;   // row within 8-row staging group
  int schunk = lane & 7;  // 16B chunk within 128B row

  for (int kt = 0; kt < K; kt += 64) {
    __syncthreads();
#pragma unroll
    for (int i = 0; i < MT / 32; i++) {
      int ra = w * (MT / 4) + i * 8;
      int r = ra + srow;
      GLOAD16(&A[(size_t)(row0 + r) * K + kt + ((schunk ^ (r & 7)) * 8)],
              &As[ra * 64]);
    }
#pragma unroll
    for (int i = 0; i < BN / 32; i++) {
      int rb = w * (BN / 4) + i * 8;
      int r = rb + srow;
      GLOAD16(&Bt[(size_t)r * K + kt + ((schunk ^ (r & 7)) * 8)],
              &Bs[rb * 64]);
    }
    __syncthreads();  // drains vmcnt before barrier
#pragma unroll
    for (int kk = 0; kk < 2; kk++) {
      short8 af[MI], bf[4];
#pragma unroll
      for (int mi = 0; mi < MI; mi++) {
        int r = wr + mi * 16 + l15;
        af[mi] = *(const short8*)&As[r * 64 + ((kk * 32 + l4 * 8) ^ ((r & 7) * 8))];
      }
#pragma unroll
      for (int ni = 0; ni < 4; ni++) {
        int r = wc + ni * 16 + l15;
        bf[ni] = *(const short8*)&Bs[r * 64 + ((kk * 32 + l4 * 8) ^ ((r & 7) * 8))];
      }
#pragma unroll
      for (int mi = 0; mi < MI; mi++)
#pragma unroll
        for (int ni = 0; ni < 4; ni++)
          acc[mi][ni] = __builtin_amdgcn_mfma_f32_16x16x32_bf16(af[mi], bf[ni],
                                                                acc[mi][ni], 0, 0, 0);
    }
  }
#pragma unroll
  for (int mi = 0; mi < MI; mi++) {
    int rbase = row0 + wr + mi * 16 + l4 * 4;
#pragma unroll
    for (int ni = 0; ni < 4; ni++) {
      int col = wc + ni * 16 + l15;
#pragma unroll
      for (int r = 0; r < 4; r++)
        C[(size_t)(rbase + r) * BN + col] = f2u(acc[mi][ni][r]);
    }
  }
  float asv[4], adv[4];
#pragma unroll
  for (int ni = 0; ni < 4; ni++) {
    asv[ni] = as_g[wc + ni * 16 + l15];
    adv[ni] = ad_g[wc + ni * 16 + l15];
  }
  int hh = (BN == 256) ? w : 0;
#pragma unroll
  for (int mi = 0; mi < MI; mi++) {
#pragma unroll
    for (int r = 0; r < 4; r++) {
      float ps = 0.f, pd = 0.f;
#pragma unroll
      for (int ni = 0; ni < 4; ni++) {
        ps += acc[mi][ni][r] * asv[ni];
        pd += acc[mi][ni][r] * adv[ni];
      }
#pragma unroll
      for (int off = 1; off < 16; off <<= 1) {
        ps += __shfl_xor(ps, off, 64);
        pd += __shfl_xor(pd, off, 64);
      }
      if (l15 == 0) {
        int row = row0 + wr + mi * 16 + l4 * 4 + r;
        a_sg[row * H + hh] = ps;
        a_dg[row * H + hh] = pd;
      }
    }
  }
}

// ---- fused logit+softmax+aggregate, H=4, two-phase (wave-parallel weights) --
// Phase-2 tables packed as float2 {weight, bitcast(src)} -> one ds_read_b64
// per edge instead of two b32 reads + two address computes.
__global__ __launch_bounds__(256) void k_agg4(
    const ushort* __restrict__ hbuf, const int2* __restrict__ epk,
    const int* __restrict__ deg, const float* __restrict__ a_s,
    const float* __restrict__ a_d, const float* __restrict__ wed,
    const float* __restrict__ bias, const float* __restrict__ bng,
    const float* __restrict__ bnb, const float* __restrict__ bnm,
    const float* __restrict__ bnv, ushort* __restrict__ xout) {
  __shared__ float2 lds_ws[4][kMD][4];  // 8 KB: {w, src} per (slot, h)
  __shared__ float lds_m[4][4][2];      // winv, selfw per h
  int tid = threadIdx.x;
  int w = tid >> 6, lane = tid & 63;
  int d = blockIdx.x * 4 + w;
  const int2* rp = &epk[(size_t)d * kMD];
  int dgt = deg[d];
  int dg = min(dgt, kMD);

  // ---- phase 1: lane = (slot0, h1); each exp computed once per (edge, head)
  int h1 = lane & 3, slot0 = lane >> 2;
  float adh1 = a_d[d * 4 + h1];
  float wdh1 = wed[h1];
  float szp = 0.f, seap = 0.f;
  for (int t = 0; t < dg; t += 16) {
    int slot = t + slot0;
    float wv = 0.f, ev = 0.f;
    if (slot < dg) {
      int2 rec = rp[slot];
      ev = __int_as_float(rec.y);
      float asv = a_s[rec.x * 4 + h1];
      wv = __expf(lrelu(asv + adh1 + ev * wdh1));
      lds_ws[w][slot][h1] = make_float2(wv, __int_as_float(rec.x));
    }
    szp += wv;
    seap += (h1 == 0) ? ev : 0.f;
  }
#pragma unroll
  for (int off = 4; off < 64; off <<= 1) {
    szp  += __shfl_xor(szp, off, 64);
    seap += __shfl_xor(seap, off, 64);
  }
  float sea = __shfl(seap, lane & 0x3C, 64);  // broadcast from h==0 lane of group
  float lea = sea / fmaxf((float)dgt, 1.f);
  float selfw1 = __expf(lrelu(a_s[d * 4 + h1] + adh1 + lea * wdh1));
  float szh = szp + selfw1;
  if (slot0 == 0) {
    lds_m[w][h1][0] = 1.f / (szh + 1e-16f);
    lds_m[w][h1][1] = selfw1;
  }

  // ---- phase 2: gather + weighted accumulate (packed {w,src} from LDS)
  int h2 = lane >> 4;
  int c0 = lane * 4;
  ushort4 vself = *(const ushort4*)&hbuf[(size_t)d * 256 + c0];  // hoisted
  float a0 = 0.f, a1 = 0.f, a2 = 0.f, a3 = 0.f;
  int k = 0;
  for (; k + 16 <= dg; k += 16) {
    float2 ws16[16];
#pragma unroll
    for (int j = 0; j < 16; j++) ws16[j] = lds_ws[w][k + j][h2];
    ushort4 v16[16];
#pragma unroll
    for (int j = 0; j < 16; j++)
      v16[j] = *(const ushort4*)&hbuf[(size_t)__float_as_int(ws16[j].y) * 256 + c0];
#pragma unroll
    for (int j = 0; j < 16; j++) {
      float wj = ws16[j].x;
      a0 += wj * bu(v16[j].x); a1 += wj * bu(v16[j].y);
      a2 += wj * bu(v16[j].z); a3 += wj * bu(v16[j].w);
    }
  }
  for (; k + 8 <= dg; k += 8) {
    float2 ws8[8];
#pragma unroll
    for (int j = 0; j < 8; j++) ws8[j] = lds_ws[w][k + j][h2];
    ushort4 v8[8];
#pragma unroll
    for (int j = 0; j < 8; j++)
      v8[j] = *(const ushort4*)&hbuf[(size_t)__float_as_int(ws8[j].y) * 256 + c0];
#pragma unroll
    for (int j = 0; j < 8; j++) {
      float wj = ws8[j].x;
      a0 += wj * bu(v8[j].x); a1 += wj * bu(v8[j].y);
      a2 += wj * bu(v8[j].z); a3 += wj * bu(v8[j].w);
    }
  }
  for (; k < dg; k++) {
    float2 ws = lds_ws[w][k][h2];
    ushort4 v0 = *(const ushort4*)&hbuf[(size_t)__float_as_int(ws.y) * 256 + c0];
    a0 += ws.x * bu(v0.x); a1 += ws.x * bu(v0.y);
    a2 += ws.x * bu(v0.z); a3 += ws.x * bu(v0.w);
  }
  // self-loop
  float winv = lds_m[w][h2][0];
  float sw   = lds_m[w][h2][1];
  a0 += sw * bu(vself.x); a1 += sw * bu(vself.y);
  a2 += sw * bu(vself.z); a3 += sw * bu(vself.w);

  float4 bi = *(const float4*)&bias[c0];
  a0 = a0 * winv + bi.x; a1 = a1 * winv + bi.y;
  a2 = a2 * winv + bi.z; a3 = a3 * winv + bi.w;
  float4 g4 = *(const float4*)&bng[c0], b4 = *(const float4*)&bnb[c0];
  float4 m4 = *(const float4*)&bnm[c0], v4 = *(const float4*)&bnv[c0];
  a0 = fmaxf((a0 - m4.x) * rsqrtf(v4.x + BN_EPS_) * g4.x + b4.x, 0.f);
  a1 = fmaxf((a1 - m4.y) * rsqrtf(v4.y + BN_EPS_) * g4.y + b4.y, 0.f);
  a2 = fmaxf((a2 - m4.z) * rsqrtf(v4.z + BN_EPS_) * g4.z + b4.z, 0.f);
  a3 = fmaxf((a3 - m4.w) * rsqrtf(v4.w + BN_EPS_) * g4.w + b4.w, 0.f);
  ushort4 o = make_ushort4(f2u(a0), f2u(a1), f2u(a2), f2u(a3));
  *(ushort4*)&xout[(size_t)d * 256 + c0] = o;
}

// ---- final agg (H=1, 64 ch) + fused per-graph mean-pool (atomics) ----------
// All 4 dsts in a block share one graph (200 % 4 == 0 -> 50 blocks/graph).
__global__ __launch_bounds__(256) void k_agg1(
    const ushort* __restrict__ hbuf, const int2* __restrict__ epk,
    const int* __restrict__ deg, const float* __restrict__ a_s,
    const float* __restrict__ a_d, const float* __restrict__ wed,
    float* __restrict__ gsum) {
  __shared__ float2 lds_ws[4][kMD];  // {w, bitcast(src)}
  __shared__ float part[4][64];
  int tid = threadIdx.x;
  int w = tid >> 6, lane = tid & 63;
  int d = blockIdx.x * 4 + w;
  const int2* rp = &epk[(size_t)d * kMD];
  int dgt = deg[d];
  int dg = min(dgt, kMD);
  float adh = a_d[d];
  float wdh = wed[0];

  // phase 1: lane = slot (kMD == 64 -> single pass)
  float wv = 0.f, ev = 0.f;
  if (lane < dg) {
    int2 rec = rp[lane];
    ev = __int_as_float(rec.y);
    wv = __expf(lrelu(a_s[rec.x] + adh + ev * wdh));
    lds_ws[w][lane] = make_float2(wv, __int_as_float(rec.x));
  }
  float szp = wv, seap = ev;
#pragma unroll
  for (int off = 1; off < 64; off <<= 1) {
    szp  += __shfl_xor(szp, off, 64);
    seap += __shfl_xor(seap, off, 64);
  }
  float lea = seap / fmaxf((float)dgt, 1.f);
  float selfw = __expf(lrelu(a_s[d] + adh + lea * wdh));
  float winv = 1.f / (szp + selfw + 1e-16f);

  // phase 2
  float vselff = bu(hbuf[(size_t)d * 64 + lane]);  // hoisted
  float acc = 0.f;
  int k = 0;
  for (; k + 16 <= dg; k += 16) {
    float2 ws16[16];
#pragma unroll
    for (int j = 0; j < 16; j++) ws16[j] = lds_ws[w][k + j];
    ushort v16[16];
#pragma unroll
    for (int j = 0; j < 16; j++)
      v16[j] = hbuf[(size_t)__float_as_int(ws16[j].y) * 64 + lane];
#pragma unroll
    for (int j = 0; j < 16; j++) acc += ws16[j].x * bu(v16[j]);
  }
  for (; k + 8 <= dg; k += 8) {
    float2 ws8[8];
#pragma unroll
    for (int j = 0; j < 8; j++) ws8[j] = lds_ws[w][k + j];
    ushort v8[8];
#pragma unroll
    for (int j = 0; j < 8; j++)
      v8[j] = hbuf[(size_t)__float_as_int(ws8[j].y) * 64 + lane];
#pragma unroll
    for (int j = 0; j < 8; j++) acc += ws8[j].x * bu(v8[j]);
  }
  for (; k < dg; k++) {
    float2 ws = lds_ws[w][k];
    acc += ws.x * bu(hbuf[(size_t)__float_as_int(ws.y) * 64 + lane]);
  }
  acc += selfw * vselff;
  acc = acc * winv;                 // node value sans bias (bias added in head)

  part[w][lane] = acc;
  __syncthreads();
  if (w == 0) {
    float s = (part[0][lane] + part[1][lane]) + (part[2][lane] + part[3][lane]);
    int g = (blockIdx.x * 4) / kNPG;
    atomicAdd(&gsum[g * 64 + lane], s);
  }
}

// ---------------- MLP head (pool sums precomputed in gsum) ----------------
__global__ void k_head(const float* __restrict__ gsum, const float* __restrict__ bias,
                       const float* __restrict__ cw1, const float* __restrict__ cb1,
                       const float* __restrict__ cw2, const float* __restrict__ cb2,
                       float* __restrict__ out) {
  __shared__ float gb[64], hb[64];
  int g = blockIdx.x, c = threadIdx.x;
  gb[c] = gsum[g * 64 + c] * (1.f / kNPG) + bias[c];
  __syncthreads();
  float s = cb1[c];
#pragma unroll 8
  for (int i = 0; i < 64; i++) s += gb[i] * cw1[i * 64 + c];
  s = 0.5f * s * (1.f + erff(s * 0.70710678118654752f));  // exact GELU
  hb[c] = s;
  __syncthreads();
  if (c < 2) {
    float o = cb2[c];
    for (int i = 0; i < 64; i++) o += hb[i] * cw2[i * 2 + c];
    out[g * 2 + c] = o;
  }
}

// ---------------- launch ----------------

extern "C" void kernel_launch(void* const* d_in, const int* in_sizes, int n_in,
                              void* d_out, int out_size, void* d_ws, size_t ws_size,
                              hipStream_t stream) {
  (void)in_sizes; (void)n_in; (void)out_size; (void)ws_size;
  const float* x  = (const float*)d_in[0];
  const int* ei   = (const int*)d_in[1];
  const float* ea = (const float*)d_in[2];
  const float *W[3], *as_[3], *ad_[3], *We[3], *ae[3], *bi[3];
  for (int l = 0; l < 3; l++) {
    W[l]   = (const float*)d_in[4 + l * 6 + 0];
    as_[l] = (const float*)d_in[4 + l * 6 + 1];
    ad_[l] = (const float*)d_in[4 + l * 6 + 2];
    We[l]  = (const float*)d_in[4 + l * 6 + 3];
    ae[l]  = (const float*)d_in[4 + l * 6 + 4];
    bi[l]  = (const float*)d_in[4 + l * 6 + 5];
  }
  const float* bng = (const float*)d_in[22];
  const float* bnb = (const float*)d_in[23];
  const float* bnm = (const float*)d_in[24];
  const float* bnv = (const float*)d_in[25];
  const float* cw1 = (const float*)d_in[26];
  const float* cb1 = (const float*)d_in[27];
  const float* cw2 = (const float*)d_in[28];
  const float* cb2 = (const float*)d_in[29];

  char* p = (char*)d_ws;
  auto alloc = [&](size_t bytes) -> void* {
    void* r = (void*)p;
    p += (bytes + 255) & ~(size_t)255;
    return r;
  };
  ushort* x2b   = (ushort*)alloc((size_t)kN * kK0 * 2);
  ushort* hbufb = (ushort*)alloc((size_t)kN * 256 * 2);
  ushort* xbA   = (ushort*)alloc((size_t)kN * 256 * 2);
  ushort* xbB   = (ushort*)alloc((size_t)kN * 256 * 2);
  ushort* Wt0   = (ushort*)alloc((size_t)kK0 * 256 * 2);
  ushort* Wt1   = (ushort*)alloc((size_t)256 * 256 * 2);
  ushort* Wt2   = (ushort*)alloc((size_t)256 * 64 * 2);
  float* a_s    = (float*)alloc((size_t)kN * 4 * 4);
  float* a_d    = (float*)alloc((size_t)kN * 4 * 4);
  int2* epk     = (int2*)alloc((size_t)kN * kMD * 8);  // 13.1 MB padded CSR
  float* wed    = (float*)alloc(256);
  int* deg      = (int*)alloc((size_t)kN * 4);         // 102400 B (256-mult)
  float* gsum   = (float*)alloc((size_t)kG * 64 * 4);  // contiguous after deg

  // 0: zero degree counters + graph accumulators in one memset
  hipMemsetAsync(deg, 0, (size_t)kN * 4 + (size_t)kG * 64 * 4, stream);
  // 1: fused prep (prep_x | Wt + wedot | per-edge degree + scatter | K-pads)
  k_pre<<<5000 + 2929, 256, 0, stream>>>(
      x, x2b, W[0], Wt0, W[1], Wt1, W[2], Wt2, We[0], ae[0], We[1], ae[1],
      We[2], ae[2], wed, ei, ea, epk, deg);
  // 2: layer-0 GEMM (K=448 padded)
  dim3 gg64m(1, kN / 64);
  k_gemm_f<256, 64><<<gg64m, 256, 0, stream>>>(x2b, Wt0, hbufb, as_[0], ad_[0],
                                               a_s, a_d, kK0);
  // 3: agg layer0
  k_agg4<<<kN / 4, 256, 0, stream>>>(hbufb, epk, deg, a_s, a_d,
                                     &wed[0], bi[0], bng, bnb, bnm, bnv, xbA);
  // 4: gemm layer1
  k_gemm_f<256, 64><<<gg64m, 256, 0, stream>>>(xbA, Wt1, hbufb, as_[1], ad_[1],
                                               a_s, a_d, 256);
  // 5: agg layer1
  k_agg4<<<kN / 4, 256, 0, stream>>>(hbufb, epk, deg, a_s, a_d,
                                     &wed[4], bi[1], bng, bnb, bnm, bnv, xbB);
  // 6: gemm layer2
  dim3 gg64(1, kN / 64);
  k_gemm_f<64, 64><<<gg64, 256, 0, stream>>>(xbB, Wt2, hbufb, as_[2], ad_[2],
                                             a_s, a_d, 256);
  // 7: agg layer2 (H=1) + fused mean-pool
  k_agg1<<<kN / 4, 256, 0, stream>>>(hbufb, epk, deg, a_s, a_d, &wed[8], gsum);
  // 8: MLP head
  k_head<<<kG, 64, 0, stream>>>(gsum, bi[2], cw1, cb1, cw2, cb2, (float*)d_out);
}

// Round 11
// 284.967 us; speedup vs baseline: 2.7245x; 1.0134x over previous
//
#include <hip/hip_runtime.h>
#include <hip/hip_bf16.h>

static const int kN  = 25600;   // nodes
static const int kE  = 409600;  // edges
static const int kG  = 128;     // graphs
static const int kNPG = 200;    // nodes per graph
static const int kIN = 200;     // raw feat dim
static const int kIN2 = 400;    // after nan-mask concat
static const int kK0 = 448;     // layer-0 K padded to 64-multiple for global_load_lds
static const int kMD = 64;      // padded CSR max degree (mean 16, sigma 4 -> 12 sigma)
#define BN_EPS_ 1e-5f

typedef __attribute__((ext_vector_type(8))) short short8;
typedef __attribute__((ext_vector_type(4))) ushort us4;
typedef __attribute__((ext_vector_type(4))) float f32x4;

__device__ __forceinline__ float bu(ushort u) {
  union { float f; unsigned u32; } x; x.u32 = ((unsigned)u) << 16; return x.f;
}
__device__ __forceinline__ ushort f2u(float v) {
  __hip_bfloat16 t = __float2bfloat16(v);  // RN
  return *(ushort*)&t;
}
__device__ __forceinline__ float wredSum(float v) {
#pragma unroll
  for (int off = 1; off < 64; off <<= 1) v += __shfl_xor(v, off, 64);
  return v;
}
__device__ __forceinline__ float lrelu(float a) { return (a > 0.f) ? a : 0.2f * a; }

// async global->LDS, 16B per lane; dest = wave-uniform base + lane*16
#define GLOAD16(g, l) __builtin_amdgcn_global_load_lds( \
    (const __attribute__((address_space(1))) unsigned int*)(g), \
    (__attribute__((address_space(3))) unsigned int*)(l), 16, 0, 0)

// ---- fused prep: prep_x | Wt + wedot | edge-degree + direct scatter | pads --
// pb regions: [0,720) Wt, [720,723) wedot, [723,2323) edges, [2323,2929) pads
__global__ void k_pre(const float* __restrict__ x, ushort* __restrict__ x2,
                      const float* __restrict__ W0, ushort* __restrict__ Wt0,
                      const float* __restrict__ W1, ushort* __restrict__ Wt1,
                      const float* __restrict__ W2, ushort* __restrict__ Wt2,
                      const float* __restrict__ We0, const float* __restrict__ ae0,
                      const float* __restrict__ We1, const float* __restrict__ ae1,
                      const float* __restrict__ We2, const float* __restrict__ ae2,
                      float* __restrict__ wed,
                      const int* __restrict__ ei, const float* __restrict__ ea,
                      int2* __restrict__ epk, int* __restrict__ deg) {
  int b = blockIdx.x, tid = threadIdx.x;
  if (b < 5000) {
    int i4 = (b * 256 + tid) * 4;          // kIN=200 divisible by 4
    int n = i4 / kIN, j = i4 - n * kIN;
    float4 v = *(const float4*)&x[i4];
    ushort o0[4], o1[4];
    float vv[4] = {v.x, v.y, v.z, v.w};
#pragma unroll
    for (int q = 0; q < 4; q++) {
      bool bad = (vv[q] != vv[q]);
      o0[q] = f2u(bad ? 0.f : vv[q]);
      o1[q] = f2u(bad ? 1.f : 0.f);
    }
    *(us4*)&x2[(size_t)n * kK0 + j] = *(us4*)o0;
    *(us4*)&x2[(size_t)n * kK0 + kIN + j] = *(us4*)o1;
    return;
  }
  int pb = b - 5000;
  if (pb >= 2323) {
    // zero the K-pad [400,448) of x2 rows and Wt0 rows (16B stores)
    int idx = (pb - 2323) * 256 + tid;
    short8 z = {0, 0, 0, 0, 0, 0, 0, 0};
    if (idx < 153600) {
      int row = idx / 6, c = idx - row * 6;
      *(short8*)&x2[(size_t)row * kK0 + kIN2 + c * 8] = z;
    } else {
      int j = idx - 153600;
      if (j < 1536) {
        int row = j / 6, c = j - row * 6;
        *(short8*)&Wt0[(size_t)row * kK0 + kIN2 + c * 8] = z;
      }
    }
    return;
  }
  if (pb >= 723) {
    // per-edge: degree count + direct scatter into padded CSR (deg pre-zeroed)
    int e = (pb - 723) * 256 + tid;
    int d = ei[kE + e];
    int s = ei[e];
    float v = ea[e];
    if (v != v) v = 0.f;
    int slot = atomicAdd(&deg[d], 1);
    if (slot < kMD) {
      int2 rec; rec.x = s; rec.y = __float_as_int(v);
      epk[(size_t)d * kMD + slot] = rec;
    }
    return;
  }
  if (pb >= 720) {
    int l = pb - 720;
    const float* We = (l == 0) ? We0 : (l == 1) ? We1 : We2;
    const float* ae = (l == 0) ? ae0 : (l == 1) ? ae1 : ae2;
    int n = (l == 2) ? 64 : 256;
    float v = (tid < n) ? We[tid] * ae[tid] : 0.f;
    v = wredSum(v);
    if ((tid & 63) == 0 && tid < n) wed[l * 4 + (tid >> 6)] = v;
    return;
  }
  int i = pb * 256 + tid;
  if (i < 102400) {
    int n = i / kIN2, k = i - n * kIN2;            // N=256, K=400 (stride 448)
    Wt0[(size_t)n * kK0 + k] = f2u(W0[(size_t)k * 256 + n]);
  } else if (i < 102400 + 65536) {
    int j = i - 102400;
    int n = j >> 8, k = j & 255;                   // N=256, K=256
    Wt1[(size_t)n * 256 + k] = f2u(W1[(size_t)k * 256 + n]);
  } else {
    int j = i - 102400 - 65536;
    int n = j >> 8, k = j & 255;                   // N=64, K=256
    Wt2[(size_t)n * 256 + k] = f2u(W2[(size_t)k * 64 + n]);
  }
}

// ---------------- MFMA GEMM + fused attention dots --------------------------
// LDS staging via global_load_lds, XOR swizzle on the SOURCE address;
// linear LDS [rows][64], 16B chunk c of row r holds global chunk c^(r&7).
// K must be a multiple of 64.
// MT=32 for the 256-wide layers: grid 800 blocks -> ~3 blocks/CU resident so
// the vmcnt(0)+barrier drain of one block overlaps another block's MFMA (m114).
template <int BN, int MT>
__global__ __launch_bounds__(256) void k_gemm_f(const ushort* __restrict__ A,
                                                const ushort* __restrict__ Bt,
                                                ushort* __restrict__ C,
                                                const float* __restrict__ as_g,
                                                const float* __restrict__ ad_g,
                                                float* __restrict__ a_sg,
                                                float* __restrict__ a_dg, int K) {
  constexpr int MI = (BN == 256) ? (MT / 16) : 1;
  constexpr int H = (BN == 256) ? 4 : 1;
  __shared__ ushort As[MT * 64];
  __shared__ ushort Bs[BN * 64];
  int tid = threadIdx.x;
  int lane = tid & 63, w = tid >> 6;
  int l15 = lane & 15, l4 = lane >> 4;
  int row0 = blockIdx.y * MT;
  int wr = (BN == 256) ? 0 : (w * 16);
  int wc = (BN == 256) ? (w * 64) : 0;
  f32x4 acc[MI][4] = {};
  int srow = lane >> 3;   // row within 8-row staging group
  int schunk = lane & 7;  // 16B chunk within 128B row

  for (int kt = 0; kt < K; kt += 64) {
    __syncthreads();
#pragma unroll
    for (int i = 0; i < MT / 32; i++) {
      int ra = w * (MT / 4) + i * 8;
      int r = ra + srow;
      GLOAD16(&A[(size_t)(row0 + r) * K + kt + ((schunk ^ (r & 7)) * 8)],
              &As[ra * 64]);
    }
#pragma unroll
    for (int i = 0; i < BN / 32; i++) {
      int rb = w * (BN / 4) + i * 8;
      int r = rb + srow;
      GLOAD16(&Bt[(size_t)r * K + kt + ((schunk ^ (r & 7)) * 8)],
              &Bs[rb * 64]);
    }
    __syncthreads();  // drains vmcnt before barrier
#pragma unroll
    for (int kk = 0; kk < 2; kk++) {
      short8 af[MI], bf[4];
#pragma unroll
      for (int mi = 0; mi < MI; mi++) {
        int r = wr + mi * 16 + l15;
        af[mi] = *(const short8*)&As[r * 64 + ((kk * 32 + l4 * 8) ^ ((r & 7) * 8))];
      }
#pragma unroll
      for (int ni = 0; ni < 4; ni++) {
        int r = wc + ni * 16 + l15;
        bf[ni] = *(const short8*)&Bs[r * 64 + ((kk * 32 + l4 * 8) ^ ((r & 7) * 8))];
      }
#pragma unroll
      for (int mi = 0; mi < MI; mi++)
#pragma unroll
        for (int ni = 0; ni < 4; ni++)
          acc[mi][ni] = __builtin_amdgcn_mfma_f32_16x16x32_bf16(af[mi], bf[ni],
                                                                acc[mi][ni], 0, 0, 0);
    }
  }
#pragma unroll
  for (int mi = 0; mi < MI; mi++) {
    int rbase = row0 + wr + mi * 16 + l4 * 4;
#pragma unroll
    for (int ni = 0; ni < 4; ni++) {
      int col = wc + ni * 16 + l15;
#pragma unroll
      for (int r = 0; r < 4; r++)
        C[(size_t)(rbase + r) * BN + col] = f2u(acc[mi][ni][r]);
    }
  }
  float asv[4], adv[4];
#pragma unroll
  for (int ni = 0; ni < 4; ni++) {
    asv[ni] = as_g[wc + ni * 16 + l15];
    adv[ni] = ad_g[wc + ni * 16 + l15];
  }
  int hh = (BN == 256) ? w : 0;
#pragma unroll
  for (int mi = 0; mi < MI; mi++) {
#pragma unroll
    for (int r = 0; r < 4; r++) {
      float ps = 0.f, pd = 0.f;
#pragma unroll
      for (int ni = 0; ni < 4; ni++) {
        ps += acc[mi][ni][r] * asv[ni];
        pd += acc[mi][ni][r] * adv[ni];
      }
#pragma unroll
      for (int off = 1; off < 16; off <<= 1) {
        ps += __shfl_xor(ps, off, 64);
        pd += __shfl_xor(pd, off, 64);
      }
      if (l15 == 0) {
        int row = row0 + wr + mi * 16 + l4 * 4 + r;
        a_sg[row * H + hh] = ps;
        a_dg[row * H + hh] = pd;
      }
    }
  }
}

// ---- fused logit+softmax+aggregate, H=4, two-phase (wave-parallel weights) --
// Phase-2 tables packed as float2 {weight, bitcast(src)} -> one ds_read_b64
// per edge instead of two b32 reads + two address computes.
__global__ __launch_bounds__(256) void k_agg4(
    const ushort* __restrict__ hbuf, const int2* __restrict__ epk,
    const int* __restrict__ deg, const float* __restrict__ a_s,
    const float* __restrict__ a_d, const float* __restrict__ wed,
    const float* __restrict__ bias, const float* __restrict__ bng,
    const float* __restrict__ bnb, const float* __restrict__ bnm,
    const float* __restrict__ bnv, ushort* __restrict__ xout) {
  __shared__ float2 lds_ws[4][kMD][4];  // 8 KB: {w, src} per (slot, h)
  __shared__ float lds_m[4][4][2];      // winv, selfw per h
  int tid = threadIdx.x;
  int w = tid >> 6, lane = tid & 63;
  int d = blockIdx.x * 4 + w;
  const int2* rp = &epk[(size_t)d * kMD];
  int dgt = deg[d];
  int dg = min(dgt, kMD);

  // ---- phase 1: lane = (slot0, h1); each exp computed once per (edge, head)
  int h1 = lane & 3, slot0 = lane >> 2;
  float adh1 = a_d[d * 4 + h1];
  float wdh1 = wed[h1];
  float szp = 0.f, seap = 0.f;
  for (int t = 0; t < dg; t += 16) {
    int slot = t + slot0;
    float wv = 0.f, ev = 0.f;
    if (slot < dg) {
      int2 rec = rp[slot];
      ev = __int_as_float(rec.y);
      float asv = a_s[rec.x * 4 + h1];
      wv = __expf(lrelu(asv + adh1 + ev * wdh1));
      lds_ws[w][slot][h1] = make_float2(wv, __int_as_float(rec.x));
    }
    szp += wv;
    seap += (h1 == 0) ? ev : 0.f;
  }
#pragma unroll
  for (int off = 4; off < 64; off <<= 1) {
    szp  += __shfl_xor(szp, off, 64);
    seap += __shfl_xor(seap, off, 64);
  }
  float sea = __shfl(seap, lane & 0x3C, 64);  // broadcast from h==0 lane of group
  float lea = sea / fmaxf((float)dgt, 1.f);
  float selfw1 = __expf(lrelu(a_s[d * 4 + h1] + adh1 + lea * wdh1));
  float szh = szp + selfw1;
  if (slot0 == 0) {
    lds_m[w][h1][0] = 1.f / (szh + 1e-16f);
    lds_m[w][h1][1] = selfw1;
  }

  // ---- phase 2: gather + weighted accumulate (packed {w,src} from LDS)
  int h2 = lane >> 4;
  int c0 = lane * 4;
  ushort4 vself = *(const ushort4*)&hbuf[(size_t)d * 256 + c0];  // hoisted
  float a0 = 0.f, a1 = 0.f, a2 = 0.f, a3 = 0.f;
  int k = 0;
  for (; k + 16 <= dg; k += 16) {
    float2 ws16[16];
#pragma unroll
    for (int j = 0; j < 16; j++) ws16[j] = lds_ws[w][k + j][h2];
    ushort4 v16[16];
#pragma unroll
    for (int j = 0; j < 16; j++)
      v16[j] = *(const ushort4*)&hbuf[(size_t)__float_as_int(ws16[j].y) * 256 + c0];
#pragma unroll
    for (int j = 0; j < 16; j++) {
      float wj = ws16[j].x;
      a0 += wj * bu(v16[j].x); a1 += wj * bu(v16[j].y);
      a2 += wj * bu(v16[j].z); a3 += wj * bu(v16[j].w);
    }
  }
  for (; k + 8 <= dg; k += 8) {
    float2 ws8[8];
#pragma unroll
    for (int j = 0; j < 8; j++) ws8[j] = lds_ws[w][k + j][h2];
    ushort4 v8[8];
#pragma unroll
    for (int j = 0; j < 8; j++)
      v8[j] = *(const ushort4*)&hbuf[(size_t)__float_as_int(ws8[j].y) * 256 + c0];
#pragma unroll
    for (int j = 0; j < 8; j++) {
      float wj = ws8[j].x;
      a0 += wj * bu(v8[j].x); a1 += wj * bu(v8[j].y);
      a2 += wj * bu(v8[j].z); a3 += wj * bu(v8[j].w);
    }
  }
  for (; k < dg; k++) {
    float2 ws = lds_ws[w][k][h2];
    ushort4 v0 = *(const ushort4*)&hbuf[(size_t)__float_as_int(ws.y) * 256 + c0];
    a0 += ws.x * bu(v0.x); a1 += ws.x * bu(v0.y);
    a2 += ws.x * bu(v0.z); a3 += ws.x * bu(v0.w);
  }
  // self-loop
  float winv = lds_m[w][h2][0];
  float sw   = lds_m[w][h2][1];
  a0 += sw * bu(vself.x); a1 += sw * bu(vself.y);
  a2 += sw * bu(vself.z); a3 += sw * bu(vself.w);

  float4 bi = *(const float4*)&bias[c0];
  a0 = a0 * winv + bi.x; a1 = a1 * winv + bi.y;
  a2 = a2 * winv + bi.z; a3 = a3 * winv + bi.w;
  float4 g4 = *(const float4*)&bng[c0], b4 = *(const float4*)&bnb[c0];
  float4 m4 = *(const float4*)&bnm[c0], v4 = *(const float4*)&bnv[c0];
  a0 = fmaxf((a0 - m4.x) * rsqrtf(v4.x + BN_EPS_) * g4.x + b4.x, 0.f);
  a1 = fmaxf((a1 - m4.y) * rsqrtf(v4.y + BN_EPS_) * g4.y + b4.y, 0.f);
  a2 = fmaxf((a2 - m4.z) * rsqrtf(v4.z + BN_EPS_) * g4.z + b4.z, 0.f);
  a3 = fmaxf((a3 - m4.w) * rsqrtf(v4.w + BN_EPS_) * g4.w + b4.w, 0.f);
  ushort4 o = make_ushort4(f2u(a0), f2u(a1), f2u(a2), f2u(a3));
  *(ushort4*)&xout[(size_t)d * 256 + c0] = o;
}

// ---- final agg (H=1, 64 ch) + fused per-graph mean-pool (atomics) ----------
// All 4 dsts in a block share one graph (200 % 4 == 0 -> 50 blocks/graph).
__global__ __launch_bounds__(256) void k_agg1(
    const ushort* __restrict__ hbuf, const int2* __restrict__ epk,
    const int* __restrict__ deg, const float* __restrict__ a_s,
    const float* __restrict__ a_d, const float* __restrict__ wed,
    float* __restrict__ gsum) {
  __shared__ float2 lds_ws[4][kMD];  // {w, bitcast(src)}
  __shared__ float part[4][64];
  int tid = threadIdx.x;
  int w = tid >> 6, lane = tid & 63;
  int d = blockIdx.x * 4 + w;
  const int2* rp = &epk[(size_t)d * kMD];
  int dgt = deg[d];
  int dg = min(dgt, kMD);
  float adh = a_d[d];
  float wdh = wed[0];

  // phase 1: lane = slot (kMD == 64 -> single pass)
  float wv = 0.f, ev = 0.f;
  if (lane < dg) {
    int2 rec = rp[lane];
    ev = __int_as_float(rec.y);
    wv = __expf(lrelu(a_s[rec.x] + adh + ev * wdh));
    lds_ws[w][lane] = make_float2(wv, __int_as_float(rec.x));
  }
  float szp = wv, seap = ev;
#pragma unroll
  for (int off = 1; off < 64; off <<= 1) {
    szp  += __shfl_xor(szp, off, 64);
    seap += __shfl_xor(seap, off, 64);
  }
  float lea = seap / fmaxf((float)dgt, 1.f);
  float selfw = __expf(lrelu(a_s[d] + adh + lea * wdh));
  float winv = 1.f / (szp + selfw + 1e-16f);

  // phase 2
  float vselff = bu(hbuf[(size_t)d * 64 + lane]);  // hoisted
  float acc = 0.f;
  int k = 0;
  for (; k + 16 <= dg; k += 16) {
    float2 ws16[16];
#pragma unroll
    for (int j = 0; j < 16; j++) ws16[j] = lds_ws[w][k + j];
    ushort v16[16];
#pragma unroll
    for (int j = 0; j < 16; j++)
      v16[j] = hbuf[(size_t)__float_as_int(ws16[j].y) * 64 + lane];
#pragma unroll
    for (int j = 0; j < 16; j++) acc += ws16[j].x * bu(v16[j]);
  }
  for (; k + 8 <= dg; k += 8) {
    float2 ws8[8];
#pragma unroll
    for (int j = 0; j < 8; j++) ws8[j] = lds_ws[w][k + j];
    ushort v8[8];
#pragma unroll
    for (int j = 0; j < 8; j++)
      v8[j] = hbuf[(size_t)__float_as_int(ws8[j].y) * 64 + lane];
#pragma unroll
    for (int j = 0; j < 8; j++) acc += ws8[j].x * bu(v8[j]);
  }
  for (; k < dg; k++) {
    float2 ws = lds_ws[w][k];
    acc += ws.x * bu(hbuf[(size_t)__float_as_int(ws.y) * 64 + lane]);
  }
  acc += selfw * vselff;
  acc = acc * winv;                 // node value sans bias (bias added in head)

  part[w][lane] = acc;
  __syncthreads();
  if (w == 0) {
    float s = (part[0][lane] + part[1][lane]) + (part[2][lane] + part[3][lane]);
    int g = (blockIdx.x * 4) / kNPG;
    atomicAdd(&gsum[g * 64 + lane], s);
  }
}

// ---------------- MLP head (pool sums precomputed in gsum) ----------------
__global__ void k_head(const float* __restrict__ gsum, const float* __restrict__ bias,
                       const float* __restrict__ cw1, const float* __restrict__ cb1,
                       const float* __restrict__ cw2, const float* __restrict__ cb2,
                       float* __restrict__ out) {
  __shared__ float gb[64], hb[64];
  int g = blockIdx.x, c = threadIdx.x;
  gb[c] = gsum[g * 64 + c] * (1.f / kNPG) + bias[c];
  __syncthreads();
  float s = cb1[c];
#pragma unroll 8
  for (int i = 0; i < 64; i++) s += gb[i] * cw1[i * 64 + c];
  s = 0.5f * s * (1.f + erff(s * 0.70710678118654752f));  // exact GELU
  hb[c] = s;
  __syncthreads();
  if (c < 2) {
    float o = cb2[c];
    for (int i = 0; i < 64; i++) o += hb[i] * cw2[i * 2 + c];
    out[g * 2 + c] = o;
  }
}

// ---------------- launch ----------------

extern "C" void kernel_launch(void* const* d_in, const int* in_sizes, int n_in,
                              void* d_out, int out_size, void* d_ws, size_t ws_size,
                              hipStream_t stream) {
  (void)in_sizes; (void)n_in; (void)out_size; (void)ws_size;
  const float* x  = (const float*)d_in[0];
  const int* ei   = (const int*)d_in[1];
  const float* ea = (const float*)d_in[2];
  const float *W[3], *as_[3], *ad_[3], *We[3], *ae[3], *bi[3];
  for (int l = 0; l < 3; l++) {
    W[l]   = (const float*)d_in[4 + l * 6 + 0];
    as_[l] = (const float*)d_in[4 + l * 6 + 1];
    ad_[l] = (const float*)d_in[4 + l * 6 + 2];
    We[l]  = (const float*)d_in[4 + l * 6 + 3];
    ae[l]  = (const float*)d_in[4 + l * 6 + 4];
    bi[l]  = (const float*)d_in[4 + l * 6 + 5];
  }
  const float* bng = (const float*)d_in[22];
  const float* bnb = (const float*)d_in[23];
  const float* bnm = (const float*)d_in[24];
  const float* bnv = (const float*)d_in[25];
  const float* cw1 = (const float*)d_in[26];
  const float* cb1 = (const float*)d_in[27];
  const float* cw2 = (const float*)d_in[28];
  const float* cb2 = (const float*)d_in[29];

  char* p = (char*)d_ws;
  auto alloc = [&](size_t bytes) -> void* {
    void* r = (void*)p;
    p += (bytes + 255) & ~(size_t)255;
    return r;
  };
  ushort* x2b   = (ushort*)alloc((size_t)kN * kK0 * 2);
  ushort* hbufb = (ushort*)alloc((size_t)kN * 256 * 2);
  ushort* xbA   = (ushort*)alloc((size_t)kN * 256 * 2);
  ushort* xbB   = (ushort*)alloc((size_t)kN * 256 * 2);
  ushort* Wt0   = (ushort*)alloc((size_t)kK0 * 256 * 2);
  ushort* Wt1   = (ushort*)alloc((size_t)256 * 256 * 2);
  ushort* Wt2   = (ushort*)alloc((size_t)256 * 64 * 2);
  float* a_s    = (float*)alloc((size_t)kN * 4 * 4);
  float* a_d    = (float*)alloc((size_t)kN * 4 * 4);
  int2* epk     = (int2*)alloc((size_t)kN * kMD * 8);  // 13.1 MB padded CSR
  float* wed    = (float*)alloc(256);
  int* deg      = (int*)alloc((size_t)kN * 4);         // 102400 B (256-mult)
  float* gsum   = (float*)alloc((size_t)kG * 64 * 4);  // contiguous after deg

  // 0: zero degree counters + graph accumulators in one memset
  hipMemsetAsync(deg, 0, (size_t)kN * 4 + (size_t)kG * 64 * 4, stream);
  // 1: fused prep (prep_x | Wt + wedot | per-edge degree + scatter | K-pads)
  k_pre<<<5000 + 2929, 256, 0, stream>>>(
      x, x2b, W[0], Wt0, W[1], Wt1, W[2], Wt2, We[0], ae[0], We[1], ae[1],
      We[2], ae[2], wed, ei, ea, epk, deg);
  // 2: layer-0 GEMM (K=448 padded, MT=32 -> 800 blocks, ~3 blocks/CU)
  dim3 gg32m(1, kN / 32);
  k_gemm_f<256, 32><<<gg32m, 256, 0, stream>>>(x2b, Wt0, hbufb, as_[0], ad_[0],
                                               a_s, a_d, kK0);
  // 3: agg layer0
  k_agg4<<<kN / 4, 256, 0, stream>>>(hbufb, epk, deg, a_s, a_d,
                                     &wed[0], bi[0], bng, bnb, bnm, bnv, xbA);
  // 4: gemm layer1 (MT=32)
  k_gemm_f<256, 32><<<gg32m, 256, 0, stream>>>(xbA, Wt1, hbufb, as_[1], ad_[1],
                                               a_s, a_d, 256);
  // 5: agg layer1
  k_agg4<<<kN / 4, 256, 0, stream>>>(hbufb, epk, deg, a_s, a_d,
                                     &wed[4], bi[1], bng, bnb, bnm, bnv, xbB);
  // 6: gemm layer2
  dim3 gg64(1, kN / 64);
  k_gemm_f<64, 64><<<gg64, 256, 0, stream>>>(xbB, Wt2, hbufb, as_[2], ad_[2],
                                             a_s, a_d, 256);
  // 7: agg layer2 (H=1) + fused mean-pool
  k_agg1<<<kN / 4, 256, 0, stream>>>(hbufb, epk, deg, a_s, a_d, &wed[8], gsum);
  // 8: MLP head
  k_head<<<kG, 64, 0, stream>>>(gsum, bi[2], cw1, cb1, cw2, cb2, (float*)d_out);
}